// Round 7
// baseline (416.208 us; speedup 1.0000x reference)
//
#include <hip/hip_runtime.h>
#include <hip/hip_bf16.h>
#include <math.h>

#define D_DIM   1024
#define P_DIM   128
#define B_ROWS  4096
#define NBANK   8192
#define C_CLS   1000
#define EPS_BN  1e-5f
#define SCALE_S 0.1f
#define MTOT    20480   // 4096 + 8192 + 8192 batched pre_project rows
#define KVSEG   16      // kv segments per side (softmax split)
#define KCH     64      // kv rows per fused chunk
#define CHUNKS  (NBANK / KVSEG / KCH)   // 8

typedef __bf16 bf16x8 __attribute__((ext_vector_type(8)));
typedef float  f32x4  __attribute__((ext_vector_type(4)));
typedef __hip_bfloat16 bf;

__device__ __forceinline__ void load_lds16(const void* gp, void* lp) {
    __builtin_amdgcn_global_load_lds(
        (__attribute__((address_space(1))) void*)gp,
        (__attribute__((address_space(3))) void*)lp, 16, 0, 0);
}

__device__ __forceinline__ int4 pack8(float4 a, float4 b) {
    union { bf h[8]; int4 v; } u;
    u.h[0] = __float2bfloat16(a.x); u.h[1] = __float2bfloat16(a.y);
    u.h[2] = __float2bfloat16(a.z); u.h[3] = __float2bfloat16(a.w);
    u.h[4] = __float2bfloat16(b.x); u.h[5] = __float2bfloat16(b.y);
    u.h[6] = __float2bfloat16(b.z); u.h[7] = __float2bfloat16(b.w);
    return u.v;
}

// ---------------------------------------------------------------------------
// bf16 MFMA GEMM: C[M,N] = A[M,K] @ B[N,K]^T (row-major bf16), 128x128 tile.
// A row stride = lda; B row stride = ldb. kchunks>1 -> split-K via blockIdx.z.
// fx==0 -> identity block map (no XCD remap); B2 != null -> M-tiles with
// by>0 use B2 instead of B (merged weight-fold dispatch).
// epi: 1 +bias,BN,ReLU -> bf16 | 3 fp32 +bias + addsrc[(gm&(ldc-1))*N+gn] |
//      4 fp32 *exp(*lsp), cols<ldc | 5 bf16 (+bias[n], +biasm[m]) |
//      6 bf16 partial at Cb + z*M*N | 8 fp32 plain partial at Cf + z*M*N
// ---------------------------------------------------------------------------
__global__ __launch_bounds__(256)
void gemm_bf16(const bf* __restrict__ A, const bf* __restrict__ B,
               const bf* __restrict__ B2,
               int M, int N, int K, int lda, int ldb,
               int kchunks, int fx, int fy, int epi,
               float* __restrict__ Cf, bf* __restrict__ Cb,
               const float* __restrict__ bias, const float* __restrict__ biasm,
               const float* __restrict__ bng, const float* __restrict__ bnb,
               const float* __restrict__ bnm, const float* __restrict__ bnv,
               const float* __restrict__ addsrc, const float* __restrict__ lsp,
               int ldc)
{
    __shared__ __align__(16) short ldsS[8192];   // 16 KB
    short* lsA = ldsS;          // [128][32]
    short* lsB = ldsS + 4096;   // [128][32]

    const int tid  = threadIdx.x;
    const int wave = tid >> 6;
    const int lane = tid & 63;
    const int wm   = wave >> 1;
    const int wn   = wave & 1;
    const int r16  = lane & 15;
    const int quad = lane >> 4;

    // XCD-aware tile remap (fx==0 -> identity)
    int bx, by;
    if (fx == 0) {
        bx = blockIdx.x; by = blockIdx.y;
    } else {
        const int gx = gridDim.x, gy = gridDim.y;
        const int l   = blockIdx.y * gx + blockIdx.x;
        const int xcd = l & 7;
        const int i0  = l >> 3;
        const int sx  = gx / fx, sy = gy / fy;
        bx = (xcd % fx) * sx + (i0 % sx);
        by = (xcd / fx) * sy + (i0 / sx);
    }
    const int bm0 = by * 128;
    const int bn0 = bx * 128;
    const bf* Bp = (B2 && by > 0) ? B2 : B;

    const int kper = K / kchunks;
    const int kbeg = blockIdx.z * kper;
    const int kend = kbeg + kper;

    f32x4 acc[4][4];
#pragma unroll
    for (int i = 0; i < 4; ++i)
#pragma unroll
        for (int j = 0; j < 4; ++j) acc[i][j] = (f32x4){0.f, 0.f, 0.f, 0.f};

    for (int k0 = kbeg; k0 < kend; k0 += 32) {
#pragma unroll
        for (int i = 0; i < 2; ++i) {
            const int s   = i * 256 + tid;
            const int row = s >> 2;
            const int cc  = (s & 3) * 8;
            const int lofs = (i * 256 + wave * 64) * 16;
            load_lds16(A + (size_t)(bm0 + row) * lda + k0 + cc, (char*)lsA + lofs);
            load_lds16(Bp + (size_t)(bn0 + row) * ldb + k0 + cc, (char*)lsB + lofs);
        }
        __syncthreads();

        bf16x8 af[4], bfr[4];
#pragma unroll
        for (int i = 0; i < 4; ++i)
            af[i] = *(const bf16x8*)(lsA + (wm * 64 + i * 16 + r16) * 32 + quad * 8);
#pragma unroll
        for (int j = 0; j < 4; ++j)
            bfr[j] = *(const bf16x8*)(lsB + (wn * 64 + j * 16 + r16) * 32 + quad * 8);
#pragma unroll
        for (int i = 0; i < 4; ++i)
#pragma unroll
            for (int j = 0; j < 4; ++j)
                acc[i][j] = __builtin_amdgcn_mfma_f32_16x16x32_bf16(
                    af[i], bfr[j], acc[i][j], 0, 0, 0);
        __syncthreads();
    }

    if (epi == 8) {
        float* dst = Cf + (size_t)blockIdx.z * M * N;
#pragma unroll
        for (int i = 0; i < 4; ++i) {
            const int gmb = bm0 + wm * 64 + i * 16 + quad * 4;
#pragma unroll
            for (int j = 0; j < 4; ++j) {
                const int gn = bn0 + wn * 64 + j * 16 + r16;
#pragma unroll
                for (int r = 0; r < 4; ++r)
                    dst[(size_t)(gmb + r) * N + gn] = acc[i][j][r];
            }
        }
        return;
    }

    if (epi == 3 || epi == 4) {
        const float lsv = (epi == 4) ? expf(*lsp) : 1.0f;
#pragma unroll
        for (int i = 0; i < 4; ++i) {
            const int gmb = bm0 + wm * 64 + i * 16 + quad * 4;
#pragma unroll
            for (int j = 0; j < 4; ++j) {
                const int gn = bn0 + wn * 64 + j * 16 + r16;
#pragma unroll
                for (int r = 0; r < 4; ++r) {
                    const int gm = gmb + r;
                    float val = acc[i][j][r];
                    if (epi == 3) {
                        Cf[(size_t)gm * N + gn] =
                            val + bias[gn] + addsrc[(size_t)(gm & (ldc - 1)) * N + gn];
                    } else {
                        if (gn < ldc) Cf[(size_t)gm * ldc + gn] = val * lsv;
                    }
                }
            }
        }
        return;
    }

    // bf16 LDS-staged store path (epi 1, 5, 6)
    bf* dst = Cb + (epi == 6 ? (size_t)blockIdx.z * M * N : 0);
    bf* my  = (bf*)(ldsS + wave * 2048);   // 4 KB per wave: [32][64] bf16

#pragma unroll
    for (int half = 0; half < 2; ++half) {
#pragma unroll
        for (int i2 = 0; i2 < 2; ++i2) {
            const int i = half * 2 + i2;
            const int gmb = bm0 + wm * 64 + i * 16 + quad * 4;
#pragma unroll
            for (int j = 0; j < 4; ++j) {
                const int gn = bn0 + wn * 64 + j * 16 + r16;
#pragma unroll
                for (int r = 0; r < 4; ++r) {
                    float val = acc[i][j][r];
                    if (epi == 1) {
                        val += bias[gn];
                        val = (val - bnm[gn]) * rsqrtf(bnv[gn] + EPS_BN) * bng[gn] + bnb[gn];
                        val = fmaxf(val, 0.f);
                    } else {
                        if (bias)  val += bias[gn];
                        if (biasm) val += biasm[gmb + r];
                    }
                    my[(i2 * 16 + quad * 4 + r) * 64 + j * 16 + r16] =
                        __float2bfloat16(val);
                }
            }
        }
#pragma unroll
        for (int it = 0; it < 4; ++it) {
            const int chunk = it * 64 + lane;
            const int lrow  = chunk >> 3;
            const int lcol  = (chunk & 7) * 8;
            const int grow  = bm0 + wm * 64 + half * 32 + lrow;
            const int gcol  = bn0 + wn * 64 + lcol;
            int4 v = *(const int4*)(my + lrow * 64 + lcol);
            *(int4*)(dst + (size_t)grow * N + gcol) = v;
        }
    }
}

// ---------------------------------------------------------------------------
// h2fuse: per 128-row tile of the 20480-row batch:
//   h1 = relu(A1*(Hp0+Hp1)+C1); h2 = relu(A2*(h1@W2^T)+C2)
//   q tiles  (r0<4096): qt = h2@Wqk^T -> qtb (h2 itself not needed in HBM)
//   bank tiles: h2 -> h2b, beta[n] = h2.vvec, transposed cols -> h2T
// (absorbs R6's posth2 dispatch + h1/h2 HBM round-trips)
// ---------------------------------------------------------------------------
__global__ __launch_bounds__(256)
void h2fuse(const float* __restrict__ Hp,     // [2][MTOT][128] fp32 partials
            const bf* __restrict__ W2b,       // [128][128]
            const bf* __restrict__ Wqk,       // [128][128]
            const float* __restrict__ bnA,    // A1|C1|A2|C2 (4x128)
            const float* __restrict__ vvecP,  // [16][128]
            bf* __restrict__ h2b, bf* __restrict__ qtb,
            float* __restrict__ beta, bf* __restrict__ h2T)
{
    __shared__ __align__(16) short lsH[16384];   // [128][128] swizzled
    __shared__ __align__(16) short lsW[16384];   // [128][128] swizzled
    __shared__ float sA1[128], sC1[128], sA2[128], sC2[128];

    const int tid  = threadIdx.x;
    const int wave = tid >> 6;
    const int lane = tid & 63;
    const int r16  = lane & 15;
    const int quad = lane >> 4;
    const int wm   = wave >> 1;
    const int wn   = wave & 1;
    const int r0   = blockIdx.x * 128;
    const bool isq = (r0 < B_ROWS);

    // stage W2 (pre-swizzled global source -> linear LDS dest)
#pragma unroll
    for (int m = 0; m < 8; ++m) {
        const int s = m * 256 + tid;
        const int row = s >> 4, pcg = s & 15;
        load_lds16(W2b + row * 128 + (pcg ^ (row & 15)) * 8,
                   (char*)lsW + (m * 256 + wave * 64) * 16);
    }
    if (tid < 128) {
        sA1[tid] = bnA[tid];       sC1[tid] = bnA[128 + tid];
        sA2[tid] = bnA[256 + tid]; sC2[tid] = bnA[384 + tid];
    }
    __syncthreads();

    // h1 tile -> lsH (swizzled bf16)
#pragma unroll
    for (int m = 0; m < 16; ++m) {
        const int s = m * 256 + tid;
        const int row = s >> 5;
        const int col = (s & 31) * 4;
        const float* p0 = Hp + (size_t)(r0 + row) * 128 + col;
        float4 x0 = *(const float4*)p0;
        float4 x1 = *(const float4*)(p0 + (size_t)MTOT * 128);
        union { bf h[4]; int2 v; } u;
        u.h[0] = __float2bfloat16(fmaxf(fmaf(x0.x + x1.x, sA1[col],     sC1[col]),     0.f));
        u.h[1] = __float2bfloat16(fmaxf(fmaf(x0.y + x1.y, sA1[col + 1], sC1[col + 1]), 0.f));
        u.h[2] = __float2bfloat16(fmaxf(fmaf(x0.z + x1.z, sA1[col + 2], sC1[col + 2]), 0.f));
        u.h[3] = __float2bfloat16(fmaxf(fmaf(x0.w + x1.w, sA1[col + 3], sC1[col + 3]), 0.f));
        const int cg = col >> 3;
        *(int2*)((bf*)lsH + row * 128 + ((cg ^ (row & 15)) << 3) + (col & 7)) = u.v;
    }
    __syncthreads();   // lsH + lsW ready

    // pass 1: acc = h1 @ W2^T
    f32x4 acc[4][4];
#pragma unroll
    for (int i = 0; i < 4; ++i)
#pragma unroll
        for (int j = 0; j < 4; ++j) acc[i][j] = (f32x4){0.f, 0.f, 0.f, 0.f};
#pragma unroll
    for (int ks = 0; ks < 4; ++ks) {
        bf16x8 af[4], bfr[4];
#pragma unroll
        for (int i = 0; i < 4; ++i) {
            const int row = wm * 64 + i * 16 + r16;
            af[i] = *(const bf16x8*)(lsH + row * 128 + ((ks * 4 + quad) ^ (row & 15)) * 8);
        }
#pragma unroll
        for (int j = 0; j < 4; ++j) {
            const int row = wn * 64 + j * 16 + r16;
            bfr[j] = *(const bf16x8*)(lsW + row * 128 + ((ks * 4 + quad) ^ (row & 15)) * 8);
        }
#pragma unroll
        for (int i = 0; i < 4; ++i)
#pragma unroll
            for (int j = 0; j < 4; ++j)
                acc[i][j] = __builtin_amdgcn_mfma_f32_16x16x32_bf16(
                    af[i], bfr[j], acc[i][j], 0, 0, 0);
    }
    __syncthreads();   // pass-1 LDS reads complete

    if (isq) {
        // stage Wqk into lsW (dead after pass 1)
#pragma unroll
        for (int m = 0; m < 8; ++m) {
            const int s = m * 256 + tid;
            const int row = s >> 4, pcg = s & 15;
            load_lds16(Wqk + row * 128 + (pcg ^ (row & 15)) * 8,
                       (char*)lsW + (m * 256 + wave * 64) * 16);
        }
    }

    // epilogue: h2 = relu(A2*acc+C2) -> lsH (swizzled, overwrites h1)
#pragma unroll
    for (int i = 0; i < 4; ++i) {
#pragma unroll
        for (int j = 0; j < 4; ++j) {
            const int gn = wn * 64 + j * 16 + r16;
            const int cg = gn >> 3, cl = gn & 7;
            const float a2 = sA2[gn], c2 = sC2[gn];
#pragma unroll
            for (int r = 0; r < 4; ++r) {
                const int row = wm * 64 + i * 16 + quad * 4 + r;
                float v = fmaxf(fmaf(acc[i][j][r], a2, c2), 0.f);
                ((bf*)lsH)[row * 128 + ((cg ^ (row & 15)) << 3) + cl] =
                    __float2bfloat16(v);
            }
        }
    }
    __syncthreads();   // lsH(h2) visible; Wqk staging drained

    if (!isq) {
        // ---- bank tile: h2 -> h2b, beta, h2T columns ----
#pragma unroll
        for (int m = 0; m < 8; ++m) {
            const int s = m * 256 + tid;
            const int row = s >> 4, cg = s & 15;
            *(int4*)(h2b + (size_t)(r0 + row) * 128 + cg * 8) =
                *(const int4*)(lsH + row * 128 + ((cg ^ (row & 15)) << 3));
        }
        // vvec into sA1 (dead); barrier before cross-thread read
        if (tid < 128) {
            float s = 0.f;
#pragma unroll
            for (int z = 0; z < 16; ++z) s += vvecP[z * 128 + tid];
            sA1[tid] = s;
        }
        __syncthreads();
        const int nb0 = r0 - B_ROWS;
        // beta: 2 threads per row
        {
            const int row = tid >> 1, hf = tid & 1;
            float s = 0.f;
#pragma unroll
            for (int g = 0; g < 8; ++g) {
                const int cg = hf * 8 + g;
                bf16x8 v = *(const bf16x8*)(lsH + row * 128 + ((cg ^ (row & 15)) << 3));
#pragma unroll
                for (int e = 0; e < 8; ++e)
                    s += __bfloat162float((bf)v[e]) * sA1[cg * 8 + e];
            }
            s += __shfl_xor(s, 1, 64);
            if (hf == 0) beta[nb0 + row] = s;
        }
        // h2T: h2T[p][nb0+n] = h2[n][p]
#pragma unroll
        for (int m = 0; m < 8; ++m) {
            const int idx = m * 256 + tid;   // 0..2047
            const int p  = idx >> 4;
            const int ng = (idx & 15) * 8;
            union { bf h[8]; int4 v; } u;
#pragma unroll
            for (int e = 0; e < 8; ++e) {
                const int n = ng + e;
                u.h[e] = ((bf*)lsH)[n * 128 + (((p >> 3) ^ (n & 15)) << 3) + (p & 7)];
            }
            *(int4*)(h2T + (size_t)p * (2 * NBANK) + nb0 + ng) = u.v;
        }
        return;
    }

    // ---- q tile: pass 2: qt = h2 @ Wqk^T ----
    f32x4 acc2[4][4];
#pragma unroll
    for (int i = 0; i < 4; ++i)
#pragma unroll
        for (int j = 0; j < 4; ++j) acc2[i][j] = (f32x4){0.f, 0.f, 0.f, 0.f};
#pragma unroll
    for (int ks = 0; ks < 4; ++ks) {
        bf16x8 af[4], bfr[4];
#pragma unroll
        for (int i = 0; i < 4; ++i) {
            const int row = wm * 64 + i * 16 + r16;
            af[i] = *(const bf16x8*)(lsH + row * 128 + ((ks * 4 + quad) ^ (row & 15)) * 8);
        }
#pragma unroll
        for (int j = 0; j < 4; ++j) {
            const int row = wn * 64 + j * 16 + r16;
            bfr[j] = *(const bf16x8*)(lsW + row * 128 + ((ks * 4 + quad) ^ (row & 15)) * 8);
        }
#pragma unroll
        for (int i = 0; i < 4; ++i)
#pragma unroll
            for (int j = 0; j < 4; ++j)
                acc2[i][j] = __builtin_amdgcn_mfma_f32_16x16x32_bf16(
                    af[i], bfr[j], acc2[i][j], 0, 0, 0);
    }
    __syncthreads();   // lsW (Wqk) reads complete before my-region overwrite

    bf* my  = (bf*)lsW + wave * 2048;   // [32][64] per wave
    bf* dst = qtb + (size_t)r0 * 128;
#pragma unroll
    for (int half = 0; half < 2; ++half) {
#pragma unroll
        for (int i2 = 0; i2 < 2; ++i2) {
            const int i = half * 2 + i2;
#pragma unroll
            for (int j = 0; j < 4; ++j)
#pragma unroll
                for (int r = 0; r < 4; ++r)
                    my[(i2 * 16 + quad * 4 + r) * 64 + j * 16 + r16] =
                        __float2bfloat16(acc2[i][j][r]);
        }
#pragma unroll
        for (int it = 0; it < 4; ++it) {
            const int chunk = it * 64 + lane;
            const int lrow  = chunk >> 3;
            const int lcol  = (chunk & 7) * 8;
            const int grow  = wm * 64 + half * 32 + lrow;
            const int gcol  = wn * 64 + lcol;
            int4 v = *(const int4*)(my + lrow * 64 + lcol);
            *(int4*)(dst + (size_t)grow * 128 + gcol) = v;
        }
    }
}

// ---------------------------------------------------------------------------
// Fused attention v3: 32 q-rows per WAVE (256/block), 64 KB LDS, 512 blocks.
// R6's 55us was LDS-BW-bound: all 8 waves re-read the same K/V fragments.
// Doubling rows/wave amortizes K/V LDS reads over 2x MFMA. i-sequential QK
// keeps VGPR ~120 so launch_bounds(512,4) holds 2 blocks/CU (16 waves).
// ---------------------------------------------------------------------------
__global__ __launch_bounds__(512, 4)
void attn_fused(const bf* __restrict__ qt,      // [4096][128]
                const bf* __restrict__ h2bank,  // [16384][128] side-major
                const bf* __restrict__ h2T,     // [128][16384]
                const float* __restrict__ beta, // [16384]
                bf* __restrict__ Ypart,         // [32][4096][128]
                float* __restrict__ rsP)        // [32][4096]
{
    __shared__ __align__(16) short lds[32768];   // 64 KB -> 2 blocks/CU
    short* lsK = lds;            // [64][128],  phys cg = cg ^ (row&15)
    short* lsV = lds + 8192;     // [128][64],  phys cg = cg ^ (row&7)
    short* lsS = lds + 16384;    // [256][64],  phys cg = cg ^ (row&7)

    const int tid  = threadIdx.x;
    const int wave = tid >> 6;
    const int lane = tid & 63;
    const int r16  = lane & 15;
    const int quad = lane >> 4;

    const int qb   = blockIdx.x >> 5;          // 16 q-blocks of 256 rows
    const int side = (blockIdx.x >> 4) & 1;
    const int seg  = blockIdx.x & 15;
    const int part = side * KVSEG + seg;
    const int nseg0 = seg * (NBANK / KVSEG);
    const bf* kbase = h2bank + (size_t)side * NBANK * P_DIM;
    const int ncol0 = side * NBANK;
    const int q0 = qb * 256 + wave * 32;

    // Q fragments in registers (wave-private 32 q-rows, loop-invariant)
    bf16x8 qreg[2][4];
#pragma unroll
    for (int i = 0; i < 2; ++i) {
        const bf* qrow = qt + (size_t)(q0 + i * 16 + r16) * P_DIM;
#pragma unroll
        for (int ks = 0; ks < 4; ++ks)
            qreg[i][ks] = *(const bf16x8*)(qrow + (ks * 4 + quad) * 8);
    }

    f32x4 yacc[2][8];
    float rsacc[2][4] = {{0.f,0.f,0.f,0.f},{0.f,0.f,0.f,0.f}};
#pragma unroll
    for (int i = 0; i < 2; ++i)
#pragma unroll
        for (int j = 0; j < 8; ++j) yacc[i][j] = (f32x4){0.f, 0.f, 0.f, 0.f};

    for (int c = 0; c < CHUNKS; ++c) {
        const int kv0 = nseg0 + c * KCH;
        __syncthreads();   // prev chunk's lsK/lsV reads done -> safe to restage
        // stage K chunk [64][128]
#pragma unroll
        for (int m = 0; m < 2; ++m) {
            const int s = m * 512 + tid;
            const int row = s >> 4, pcg = s & 15;
            const int lcg = pcg ^ (row & 15);
            load_lds16(kbase + (size_t)(kv0 + row) * P_DIM + lcg * 8,
                       (char*)lsK + (m * 512 + wave * 64) * 16);
        }
        // stage V chunk [128][64] from h2T
#pragma unroll
        for (int m = 0; m < 2; ++m) {
            const int s = m * 512 + tid;
            const int row = s >> 3, pcg = s & 7;
            const int lcg = pcg ^ (row & 7);
            load_lds16(h2T + (size_t)row * (2 * NBANK) + ncol0 + kv0 + lcg * 8,
                       (char*)lsV + (m * 512 + wave * 64) * 16);
        }
        __syncthreads();   // staging complete

        // QK + exp per 16-row group (i-sequential: sacc stays at 16 VGPR)
#pragma unroll
        for (int i = 0; i < 2; ++i) {
            f32x4 sacc[4];
#pragma unroll
            for (int j = 0; j < 4; ++j) sacc[j] = (f32x4){0.f, 0.f, 0.f, 0.f};
#pragma unroll
            for (int ks = 0; ks < 4; ++ks)
#pragma unroll
                for (int j = 0; j < 4; ++j) {
                    const int kr = j * 16 + r16;
                    bf16x8 bfr = *(const bf16x8*)(lsK + kr * 128 +
                                                  ((ks * 4 + quad) ^ (kr & 15)) * 8);
                    sacc[j] = __builtin_amdgcn_mfma_f32_16x16x32_bf16(
                        qreg[i][ks], bfr, sacc[j], 0, 0, 0);
                }
            // exp -> lsS (wave-private rows; no barrier needed before PV)
#pragma unroll
            for (int j = 0; j < 4; ++j) {
                const int col = j * 16 + r16;
                const float bv = beta[(size_t)side * NBANK + kv0 + col];
                const int cg = col >> 3, cl = col & 7;
#pragma unroll
                for (int r = 0; r < 4; ++r) {
                    const int row = wave * 32 + i * 16 + quad * 4 + r;
                    float v = __expf(SCALE_S * (sacc[j][r] + bv));
                    rsacc[i][r] += v;
                    ((bf*)lsS)[row * 64 + ((cg ^ (row & 7)) << 3) + cl] =
                        __float2bfloat16(v);
                }
            }
        }

        // PV: Y[32][128] += S[32][64] @ V (pb shared across both row groups)
#pragma unroll
        for (int ks = 0; ks < 2; ++ks) {
            const int sr0 = wave * 32 + r16, sr1 = sr0 + 16;
            bf16x8 pa0 = *(const bf16x8*)(lsS + sr0 * 64 +
                                          ((ks * 4 + quad) ^ (sr0 & 7)) * 8);
            bf16x8 pa1 = *(const bf16x8*)(lsS + sr1 * 64 +
                                          ((ks * 4 + quad) ^ (sr1 & 7)) * 8);
#pragma unroll
            for (int j = 0; j < 8; ++j) {
                const int vr = j * 16 + r16;
                bf16x8 pb = *(const bf16x8*)(lsV + vr * 64 +
                                             ((ks * 4 + quad) ^ (vr & 7)) * 8);
                yacc[0][j] = __builtin_amdgcn_mfma_f32_16x16x32_bf16(
                    pa0, pb, yacc[0][j], 0, 0, 0);
                yacc[1][j] = __builtin_amdgcn_mfma_f32_16x16x32_bf16(
                    pa1, pb, yacc[1][j], 0, 0, 0);
            }
        }
    }

    // rowsum partials: reduce across the 16-lane r16 group; rows wave-private
#pragma unroll
    for (int i = 0; i < 2; ++i) {
#pragma unroll
        for (int r = 0; r < 4; ++r) {
            float s = rsacc[i][r];
            s += __shfl_xor(s, 1, 64);
            s += __shfl_xor(s, 2, 64);
            s += __shfl_xor(s, 4, 64);
            s += __shfl_xor(s, 8, 64);
            rsacc[i][r] = s;
        }
        if (r16 == 0)
            *(float4*)(rsP + (size_t)part * B_ROWS + q0 + i * 16 + quad * 4) =
                (float4){rsacc[i][0], rsacc[i][1], rsacc[i][2], rsacc[i][3]};
    }

    // Y partial store via per-wave LDS staging (whole LDS dead after barrier)
    __syncthreads();
    bf* my = (bf*)lds + wave * 4096;   // [32][128] bf16 = 8 KB per wave
#pragma unroll
    for (int i = 0; i < 2; ++i)
#pragma unroll
        for (int j = 0; j < 8; ++j)
#pragma unroll
            for (int r = 0; r < 4; ++r)
                my[(i * 16 + quad * 4 + r) * 128 + j * 16 + r16] =
                    __float2bfloat16(yacc[i][j][r]);
    bf* dst = Ypart + (size_t)part * B_ROWS * P_DIM + (size_t)q0 * P_DIM;
#pragma unroll
    for (int it = 0; it < 8; ++it) {
        const int chunk = it * 64 + lane;       // 0..511 int4s
        const int lrow  = chunk >> 4;
        const int lcol  = (chunk & 15) * 8;
        *(int4*)(dst + (size_t)lrow * P_DIM + lcol) =
            *(const int4*)(my + lrow * 128 + lcol);
    }
}

// ---------------------------------------------------------------------------
// prep mega-kernel: all input-only transforms in ONE dispatch (range-split).
// ---------------------------------------------------------------------------
#define PG0 10240   // convX
#define PG1 584     // convW
#define PG2 64      // convW3T
#define PG3 512     // ftpad
#define PG4 8       // vvecP partials
#define PG5 256     // bvp
#define PG6 1       // folded BN coefficients A1|C1|A2|C2

__global__ __launch_bounds__(256)
void prep(const float* __restrict__ Fv, const float* __restrict__ Fvs,
          const float* __restrict__ Fvt,
          const float* __restrict__ W1, const float* __restrict__ W2,
          const float* __restrict__ Wp,
          const float* __restrict__ W3, const float* __restrict__ b3,
          const float* __restrict__ bp, const float* __restrict__ Ft,
          const float* __restrict__ b1, const float* __restrict__ g1,
          const float* __restrict__ be1, const float* __restrict__ m1,
          const float* __restrict__ v1,
          const float* __restrict__ b2, const float* __restrict__ g2,
          const float* __restrict__ be2, const float* __restrict__ m2,
          const float* __restrict__ v2,
          bf* __restrict__ Xb, bf* __restrict__ W1b, bf* __restrict__ W2b,
          bf* __restrict__ Wpb,
          bf* __restrict__ Tq, bf* __restrict__ Tk, bf* __restrict__ Tv,
          bf* __restrict__ Ftb,
          float* __restrict__ vvecP, float* __restrict__ bvp,
          float* __restrict__ bnA)
{
    const int tid = threadIdx.x;
    int b = blockIdx.x;
    if (b < PG0) {                       // ---- convX: Fv|Fvs|Fvt -> bf16
        int i = (b * 256 + tid) * 8;
        const int n0 = B_ROWS * D_DIM, n1 = n0 + NBANK * D_DIM;
        const float* src; int off;
        if (i < n0)      { src = Fv;  off = i; }
        else if (i < n1) { src = Fvs; off = i - n0; }
        else             { src = Fvt; off = i - n1; }
        float4 a = *(const float4*)(src + off);
        float4 c = *(const float4*)(src + off + 4);
        *(int4*)(Xb + i) = pack8(a, c);
        return;
    }
    if ((b -= PG0) < PG1) {              // ---- convW: W1|W2|Wp -> bf16
        int i = (b * 256 + tid) * 8;
        const int n1 = P_DIM * D_DIM, n2 = n1 + P_DIM * P_DIM;
        const float* src; bf* dst; int off;
        if (i < n1)      { src = W1; dst = W1b; off = i; }
        else if (i < n2) { src = W2; dst = W2b; off = i - n1; }
        else             { src = Wp; dst = Wpb; off = i - n2; }
        float4 a = *(const float4*)(src + off);
        float4 c = *(const float4*)(src + off + 4);
        *(int4*)(dst + off) = pack8(a, c);
        return;
    }
    if ((b -= PG1) < PG2) {              // ---- convW3T: Txx[p,d] = W3[3d+x,p]
        int i = (b * 256 + tid) * 8;
        int p = i >> 10, d0 = i & 1023;
        union { bf h[8]; int4 v; } uq, uk, uv;
#pragma unroll
        for (int j = 0; j < 8; ++j) {
            const float* r = W3 + (size_t)3 * (d0 + j) * P_DIM + p;
            uq.h[j] = __float2bfloat16(r[0]);
            uk.h[j] = __float2bfloat16(r[P_DIM]);
            uv.h[j] = __float2bfloat16(r[2 * P_DIM]);
        }
        *(int4*)(Tq + i) = uq.v;
        *(int4*)(Tk + i) = uk.v;
        *(int4*)(Tv + i) = uv.v;
        return;
    }
    if ((b -= PG2) < PG3) {              // ---- ftpad
        int i = (b * 256 + tid) * 8;
        int row = i >> 10, col = i & 1023;
        if (row < C_CLS) {
            float4 a = *(const float4*)(Ft + (size_t)row * D_DIM + col);
            float4 c = *(const float4*)(Ft + (size_t)row * D_DIM + col + 4);
            *(int4*)(Ftb + i) = pack8(a, c);
        } else {
            *(int4*)(Ftb + i) = (int4){0, 0, 0, 0};
        }
        return;
    }
    if ((b -= PG3) < PG4) {              // ---- vvecP partials of W3k^T b3q
        const int p = tid & 127, hf = tid >> 7;
        const int dbase = b * 128 + hf * 64;
        float s = 0.f;
        for (int dd = 0; dd < 64; ++dd) {
            const int d = dbase + dd;
            s = fmaf(b3[3 * d], W3[(size_t)(3 * d + 1) * P_DIM + p], s);
        }
        vvecP[(b * 2 + hf) * P_DIM + p] = s;
        return;
    }
    if ((b -= PG4) < PG5) {              // ---- bvp[o] = Wp[o,:].b3v + bp[o]
        const int wave = tid >> 6, lane = tid & 63;
        const int o = b * 4 + wave;
        const float* r = Wp + (size_t)o * D_DIM;
        float s = 0.f;
        for (int i = lane; i < D_DIM; i += 64) s = fmaf(r[i], b3[3 * i + 2], s);
        for (int off = 32; off > 0; off >>= 1) s += __shfl_down(s, off, 64);
        if (lane == 0) bvp[o] = s + bp[o];
        return;
    }
    // ---- folded BN coefficients
    if (tid < 128) {
        float a1 = g1[tid] * rsqrtf(v1[tid] + EPS_BN);
        bnA[tid]       = a1;
        bnA[128 + tid] = (b1[tid] - m1[tid]) * a1 + be1[tid];
        float a2 = g2[tid] * rsqrtf(v2[tid] + EPS_BN);
        bnA[256 + tid] = a2;
        bnA[384 + tid] = (b2[tid] - m2[tid]) * a2 + be2[tid];
    }
}

// fused reduce for the merged weight-fold GEMM: WWp = [8][1152][128] bf16;
// rows 0-127 of each part -> Wqk, rows 128-1151 -> Wpv.
__global__ __launch_bounds__(256)
void reduceWW(const bf* __restrict__ WWp,
              bf* __restrict__ Wqk, bf* __restrict__ Wpv)
{
    const int tid = threadIdx.x;
    const size_t pstride = (size_t)1152 * 128;
    if (blockIdx.x < 8) {
        int i = (blockIdx.x * 256 + tid) * 8;          // < 16384
        float s[8] = {};
        for (int z = 0; z < 8; ++z) {
            union { int4 v; bf h[8]; } u;
            u.v = *(const int4*)(WWp + (size_t)z * pstride + i);
#pragma unroll
            for (int e = 0; e < 8; ++e) s[e] += __bfloat162float(u.h[e]);
        }
        union { bf h[8]; int4 v; } o;
#pragma unroll
        for (int e = 0; e < 8; ++e) o.h[e] = __float2bfloat16(s[e]);
        *(int4*)(Wqk + i) = o.v;
    } else {
        int i = ((blockIdx.x - 8) * 256 + tid) * 8;    // < 131072
        float s[8] = {};
        for (int z = 0; z < 8; ++z) {
            union { int4 v; bf h[8]; } u;
            u.v = *(const int4*)(WWp + (size_t)z * pstride + 16384 + i);
#pragma unroll
            for (int e = 0; e < 8; ++e) s[e] += __bfloat162float(u.h[e]);
        }
        union { bf h[8]; int4 v; } o;
#pragma unroll
        for (int e = 0; e < 8; ++e) o.h[e] = __float2bfloat16(s[e]);
        *(int4*)(Wpv + i) = o.v;
    }
}

// reduceY: Yhat[s][b][p] = sum_z parts[s*16+z][b][p] / (sum_g rsP[s*16+g][b])
__global__ __launch_bounds__(256)
void reduceY(const bf* __restrict__ parts, const float* __restrict__ rsP,
             bf* __restrict__ Yhat)
{
    int j = (blockIdx.x * 256 + threadIdx.x) * 8;      // < 2*B_ROWS*P_DIM
    const int s = j >> 19;                             // B_ROWS*P_DIM = 2^19
    const int qrow = (j >> 7) & (B_ROWS - 1);
    float rs = 0.f;
#pragma unroll
    for (int g = 0; g < KVSEG; ++g)
        rs += rsP[(size_t)(s * KVSEG + g) * B_ROWS + qrow];
    const bf* p = parts + (size_t)s * KVSEG * 524288 + (size_t)(j & 524287);
    float acc[8] = {};
    for (int z = 0; z < KVSEG; ++z) {
        union { int4 v; bf h[8]; } u;
        u.v = *(const int4*)(p + (size_t)z * 524288);
#pragma unroll
        for (int e = 0; e < 8; ++e) acc[e] += __bfloat162float(u.h[e]);
    }
    const float inv = 1.0f / rs;
    union { bf h[8]; int4 v; } o;
#pragma unroll
    for (int e = 0; e < 8; ++e) o.h[e] = __float2bfloat16(acc[e] * inv);
    *(int4*)(Yhat + j) = o.v;
}

// dual row L2-normalize + bf16 out
__global__ __launch_bounds__(256)
void rownorm2b(const float* __restrict__ G, bf* __restrict__ out)
{
    __shared__ float red[16];
    const int tid = threadIdx.x;
    const float* ps = G + (size_t)blockIdx.x * D_DIM;
    const float* pt = ps + (size_t)B_ROWS * D_DIM;
    float4 a = *(const float4*)(ps + tid * 4);
    float4 c = *(const float4*)(pt + tid * 4);
    float sa = a.x * a.x + a.y * a.y + a.z * a.z + a.w * a.w;
    float sb = c.x * c.x + c.y * c.y + c.z * c.z + c.w * c.w;
    for (int s = 32; s > 0; s >>= 1) {
        sa += __shfl_down(sa, s, 64);
        sb += __shfl_down(sb, s, 64);
    }
    if ((tid & 63) == 0) { red[tid >> 6] = sa; red[8 + (tid >> 6)] = sb; }
    __syncthreads();
    if (tid == 0) {
        float ta = 0.f, tb = 0.f;
        for (int w = 0; w < 4; ++w) { ta += red[w]; tb += red[8 + w]; }
        red[4] = rsqrtf(ta); red[12] = rsqrtf(tb);
    }
    __syncthreads();
    const float ia = red[4], ib = red[12];
    union { bf h[4]; int2 v; } o;
    o.h[0] = __float2bfloat16(a.x * ia + c.x * ib);
    o.h[1] = __float2bfloat16(a.y * ia + c.y * ib);
    o.h[2] = __float2bfloat16(a.z * ia + c.z * ib);
    o.h[3] = __float2bfloat16(a.w * ia + c.w * ib);
    *(int2*)(out + (size_t)blockIdx.x * D_DIM + tid * 4) = o.v;
}

// ---------------------------------------------------------------------------
// R7: attn_fused 32 rows/wave (LDS-BW fix); posth2 folded into h2fuse;
// weight-fold GEMMs merged into one dispatch. 10 dispatches total.
// ---------------------------------------------------------------------------
extern "C" void kernel_launch(void* const* d_in, const int* in_sizes, int n_in,
                              void* d_out, int out_size, void* d_ws, size_t ws_size,
                              hipStream_t stream)
{
    (void)in_sizes; (void)n_in; (void)out_size; (void)ws_size;

    const float* Ft  = (const float*)d_in[0];
    const float* Fv  = (const float*)d_in[1];
    const float* Fvs = (const float*)d_in[2];
    const float* Fvt = (const float*)d_in[3];
    const float* W1  = (const float*)d_in[4];
    const float* b1  = (const float*)d_in[5];
    const float* g1  = (const float*)d_in[6];
    const float* be1 = (const float*)d_in[7];
    const float* m1  = (const float*)d_in[8];
    const float* v1  = (const float*)d_in[9];
    const float* W2  = (const float*)d_in[10];
    const float* b2  = (const float*)d_in[11];
    const float* g2  = (const float*)d_in[12];
    const float* be2 = (const float*)d_in[13];
    const float* m2  = (const float*)d_in[14];
    const float* v2  = (const float*)d_in[15];
    const float* W3  = (const float*)d_in[16];
    const float* b3  = (const float*)d_in[17];
    const float* Wp  = (const float*)d_in[18];
    const float* bp  = (const float*)d_in[19];
    const float* ls  = (const float*)d_in[20];

    char* base = (char*)d_ws;
    size_t o = 0;
    auto take = [&](size_t s) { size_t r = o; o += (s + 255) & ~(size_t)255; return r; };

    // persistent (~25 MB). NOTE: W3kT and Wpb MUST be contiguous (merged fold
    // GEMM treats them as one 1152-row A matrix; sizes are 256B-multiples).
    bf* qtb   = (bf*)(base + take((size_t)B_ROWS * P_DIM * 2));
    bf* h2T   = (bf*)(base + take((size_t)P_DIM * 2 * NBANK * 2));
    bf* Yhat  = (bf*)(base + take((size_t)2 * B_ROWS * P_DIM * 2));
    bf* Ftb   = (bf*)(base + take((size_t)D_DIM * D_DIM * 2));
    bf* W3qT  = (bf*)(base + take((size_t)P_DIM * D_DIM * 2));
    bf* W3kT  = (bf*)(base + take((size_t)P_DIM * D_DIM * 2));
    bf* Wpb   = (bf*)(base + take((size_t)D_DIM * D_DIM * 2));   // after W3kT!
    bf* W3vT  = (bf*)(base + take((size_t)P_DIM * D_DIM * 2));
    bf* Wqk   = (bf*)(base + take((size_t)P_DIM * P_DIM * 2));
    bf* Wpvb  = (bf*)(base + take((size_t)D_DIM * P_DIM * 2));
    bf* W1b   = (bf*)(base + take((size_t)P_DIM * D_DIM * 2));
    bf* W2b   = (bf*)(base + take((size_t)P_DIM * P_DIM * 2));
    bf* h2b   = (bf*)(base + take((size_t)MTOT * P_DIM * 2));
    bf* WWp   = (bf*)(base + take((size_t)8 * 1152 * P_DIM * 2));
    float* vvecP = (float*)(base + take((size_t)16 * P_DIM * 4));
    float* beta  = (float*)(base + take((size_t)2 * NBANK * 4));
    float* bvp   = (float*)(base + take(D_DIM * 4));
    float* bnA   = (float*)(base + take(4 * P_DIM * 4));
    float* rsP   = (float*)(base + take((size_t)2 * KVSEG * B_ROWS * 4));

    // scratch region (aliased across phases)
    const size_t Dbase = o;
    bf*    Xb    = (bf*)(base + Dbase);                                  // 40 MB
    float* Hp    = (float*)(base + Dbase + (size_t)MTOT * D_DIM * 2);    // 21 MB
    bf*    Opart = (bf*)(base + Dbase + (size_t)64 * 1024 * 1024);       // 32 MB
    float* G     = (float*)(base + Dbase);                               // 32 MB
    bf*    Fsumb = (bf*)(base + Dbase + (size_t)2 * B_ROWS * D_DIM * 4); // 8 MB

    auto gemm = [&](const bf* A, const bf* B, const bf* B2,
                    int M, int N, int K, int lda, int ldb,
                    int kch, int fx, int fy, int epi, float* Cf, bf* Cb,
                    const float* bias, const float* biasm,
                    const float* bg, const float* bb, const float* bm, const float* bv,
                    const float* addsrc, const float* lsp, int ldc) {
        gemm_bf16<<<dim3(N / 128, M / 128, kch), dim3(256), 0, stream>>>(
            A, B, B2, M, N, K, lda, ldb, kch, fx, fy, epi, Cf, Cb, bias, biasm,
            bg, bb, bm, bv, addsrc, lsp, ldc);
    };

    // 1) prep: all input-only transforms + folded BN coefficients
    prep<<<dim3(PG0 + PG1 + PG2 + PG3 + PG4 + PG5 + PG6), dim3(256), 0, stream>>>(
        Fv, Fvs, Fvt, W1, W2, Wp, W3, b3, bp, Ft,
        b1, g1, be1, m1, v1, b2, g2, be2, m2, v2,
        Xb, W1b, W2b, Wpb, W3qT, W3kT, W3vT, Ftb, vvecP, bvp, bnA);

    // 2) merged weight folds: A = [W3kT; Wpb] (1152 rows), B tile 0 = W3qT
    //    (-> Wqk rows), tiles 1-8 = W3vT (-> Wpv rows); split-K 8.
    gemm(W3kT, W3qT, W3vT, 1152, P_DIM, D_DIM, D_DIM, D_DIM, 8, 0, 0, 6,
         nullptr, WWp, nullptr, nullptr, nullptr, nullptr, nullptr, nullptr,
         nullptr, nullptr, 0);
    // 3) fused reduces
    reduceWW<<<dim3(72), dim3(256), 0, stream>>>(WWp, Wqk, Wpvb);

    // 4) pre_project GEMM1, split-K fp32 partials (epi 8)
    gemm(Xb, W1b, nullptr, MTOT, P_DIM, D_DIM, D_DIM, D_DIM, 2, 1, 8, 8,
         Hp, nullptr, nullptr, nullptr, nullptr, nullptr, nullptr, nullptr,
         nullptr, nullptr, 0);
    // 5) h2fuse: partial-sum + BN1/ReLU + GEMM2 + BN2/ReLU + {Qtilde | beta,h2T}
    h2fuse<<<dim3(MTOT / 128), dim3(256), 0, stream>>>(
        Hp, W2b, Wqk, bnA, vvecP, h2b, qtb, beta, h2T);

    // 6) fused attention: S in LDS only; Y/rowsum seg partials
    attn_fused<<<dim3(2 * KVSEG * (B_ROWS / 256)), dim3(512), 0, stream>>>(
        qtb, h2b + (size_t)B_ROWS * P_DIM, h2T, beta, Opart, rsP);
    // 7) fold segments + softmax normalize -> Yhat [2*B_ROWS,128]
    reduceY<<<dim3(2 * B_ROWS * P_DIM / 2048), dim3(256), 0, stream>>>(
        Opart, rsP, Yhat);

    // 8) combined post-project (K=128) + residual
    gemm(Yhat, Wpvb, nullptr, 2 * B_ROWS, D_DIM, P_DIM, P_DIM, P_DIM, 1, 1, 8, 3,
         G, nullptr, bvp, nullptr, nullptr, nullptr, nullptr, nullptr, Fv,
         nullptr, B_ROWS);
    // 9) dual rownorm -> bf16
    rownorm2b<<<dim3(B_ROWS), dim3(256), 0, stream>>>(G, Fsumb);
    // 10) logits
    gemm(Fsumb, Ftb, nullptr, B_ROWS, D_DIM, D_DIM, D_DIM, D_DIM, 1, 1, 8, 4,
         (float*)d_out, nullptr, nullptr, nullptr, nullptr, nullptr, nullptr,
         nullptr, nullptr, ls, C_CLS);
}

// Round 8
// 375.514 us; speedup vs baseline: 1.1084x; 1.1084x over previous
//
#include <hip/hip_runtime.h>
#include <hip/hip_bf16.h>
#include <math.h>

#define D_DIM   1024
#define P_DIM   128
#define B_ROWS  4096
#define NBANK   8192
#define C_CLS   1000
#define EPS_BN  1e-5f
#define SCALE_S 0.1f
#define MTOT    20480   // 4096 + 8192 + 8192 batched pre_project rows
#define KVSEG   16      // kv segments per side (softmax split)
#define KCH     64      // kv rows per fused chunk
#define CHUNKS  (NBANK / KVSEG / KCH)   // 8

typedef __bf16 bf16x8 __attribute__((ext_vector_type(8)));
typedef float  f32x4  __attribute__((ext_vector_type(4)));
typedef __hip_bfloat16 bf;

__device__ __forceinline__ void load_lds16(const void* gp, void* lp) {
    __builtin_amdgcn_global_load_lds(
        (__attribute__((address_space(1))) void*)gp,
        (__attribute__((address_space(3))) void*)lp, 16, 0, 0);
}

__device__ __forceinline__ int4 pack8(float4 a, float4 b) {
    union { bf h[8]; int4 v; } u;
    u.h[0] = __float2bfloat16(a.x); u.h[1] = __float2bfloat16(a.y);
    u.h[2] = __float2bfloat16(a.z); u.h[3] = __float2bfloat16(a.w);
    u.h[4] = __float2bfloat16(b.x); u.h[5] = __float2bfloat16(b.y);
    u.h[6] = __float2bfloat16(b.z); u.h[7] = __float2bfloat16(b.w);
    return u.v;
}

// ---------------------------------------------------------------------------
// bf16 MFMA GEMM: C[M,N] = A[M,K] @ B[N,K]^T (row-major bf16), 128x128 tile.
// A row stride = lda; B row stride = ldb. kchunks>1 -> split-K via blockIdx.z.
// fx==0 -> identity block map (no XCD remap); B2 != null -> M-tiles with
// by>0 use B2 instead of B (merged weight-fold dispatch).
// epi: 1 +bias,BN,ReLU -> bf16 | 3 fp32 +bias + addsrc[(gm&(ldc-1))*N+gn] |
//      4 fp32 *exp(*lsp), cols<ldc | 5 bf16 (+bias[n], +biasm[m]) |
//      6 bf16 partial at Cb + z*M*N | 8 fp32 plain partial at Cf + z*M*N
// ---------------------------------------------------------------------------
__global__ __launch_bounds__(256)
void gemm_bf16(const bf* __restrict__ A, const bf* __restrict__ B,
               const bf* __restrict__ B2,
               int M, int N, int K, int lda, int ldb,
               int kchunks, int fx, int fy, int epi,
               float* __restrict__ Cf, bf* __restrict__ Cb,
               const float* __restrict__ bias, const float* __restrict__ biasm,
               const float* __restrict__ bng, const float* __restrict__ bnb,
               const float* __restrict__ bnm, const float* __restrict__ bnv,
               const float* __restrict__ addsrc, const float* __restrict__ lsp,
               int ldc)
{
    __shared__ __align__(16) short ldsS[8192];   // 16 KB
    short* lsA = ldsS;          // [128][32]
    short* lsB = ldsS + 4096;   // [128][32]

    const int tid  = threadIdx.x;
    const int wave = tid >> 6;
    const int lane = tid & 63;
    const int wm   = wave >> 1;
    const int wn   = wave & 1;
    const int r16  = lane & 15;
    const int quad = lane >> 4;

    // XCD-aware tile remap (fx==0 -> identity)
    int bx, by;
    if (fx == 0) {
        bx = blockIdx.x; by = blockIdx.y;
    } else {
        const int gx = gridDim.x, gy = gridDim.y;
        const int l   = blockIdx.y * gx + blockIdx.x;
        const int xcd = l & 7;
        const int i0  = l >> 3;
        const int sx  = gx / fx, sy = gy / fy;
        bx = (xcd % fx) * sx + (i0 % sx);
        by = (xcd / fx) * sy + (i0 / sx);
    }
    const int bm0 = by * 128;
    const int bn0 = bx * 128;
    const bf* Bp = (B2 && by > 0) ? B2 : B;

    const int kper = K / kchunks;
    const int kbeg = blockIdx.z * kper;
    const int kend = kbeg + kper;

    f32x4 acc[4][4];
#pragma unroll
    for (int i = 0; i < 4; ++i)
#pragma unroll
        for (int j = 0; j < 4; ++j) acc[i][j] = (f32x4){0.f, 0.f, 0.f, 0.f};

    for (int k0 = kbeg; k0 < kend; k0 += 32) {
#pragma unroll
        for (int i = 0; i < 2; ++i) {
            const int s   = i * 256 + tid;
            const int row = s >> 2;
            const int cc  = (s & 3) * 8;
            const int lofs = (i * 256 + wave * 64) * 16;
            load_lds16(A + (size_t)(bm0 + row) * lda + k0 + cc, (char*)lsA + lofs);
            load_lds16(Bp + (size_t)(bn0 + row) * ldb + k0 + cc, (char*)lsB + lofs);
        }
        __syncthreads();

        bf16x8 af[4], bfr[4];
#pragma unroll
        for (int i = 0; i < 4; ++i)
            af[i] = *(const bf16x8*)(lsA + (wm * 64 + i * 16 + r16) * 32 + quad * 8);
#pragma unroll
        for (int j = 0; j < 4; ++j)
            bfr[j] = *(const bf16x8*)(lsB + (wn * 64 + j * 16 + r16) * 32 + quad * 8);
#pragma unroll
        for (int i = 0; i < 4; ++i)
#pragma unroll
            for (int j = 0; j < 4; ++j)
                acc[i][j] = __builtin_amdgcn_mfma_f32_16x16x32_bf16(
                    af[i], bfr[j], acc[i][j], 0, 0, 0);
        __syncthreads();
    }

    if (epi == 8) {
        float* dst = Cf + (size_t)blockIdx.z * M * N;
#pragma unroll
        for (int i = 0; i < 4; ++i) {
            const int gmb = bm0 + wm * 64 + i * 16 + quad * 4;
#pragma unroll
            for (int j = 0; j < 4; ++j) {
                const int gn = bn0 + wn * 64 + j * 16 + r16;
#pragma unroll
                for (int r = 0; r < 4; ++r)
                    dst[(size_t)(gmb + r) * N + gn] = acc[i][j][r];
            }
        }
        return;
    }

    if (epi == 3 || epi == 4) {
        const float lsv = (epi == 4) ? expf(*lsp) : 1.0f;
#pragma unroll
        for (int i = 0; i < 4; ++i) {
            const int gmb = bm0 + wm * 64 + i * 16 + quad * 4;
#pragma unroll
            for (int j = 0; j < 4; ++j) {
                const int gn = bn0 + wn * 64 + j * 16 + r16;
#pragma unroll
                for (int r = 0; r < 4; ++r) {
                    const int gm = gmb + r;
                    float val = acc[i][j][r];
                    if (epi == 3) {
                        Cf[(size_t)gm * N + gn] =
                            val + bias[gn] + addsrc[(size_t)(gm & (ldc - 1)) * N + gn];
                    } else {
                        if (gn < ldc) Cf[(size_t)gm * ldc + gn] = val * lsv;
                    }
                }
            }
        }
        return;
    }

    // bf16 LDS-staged store path (epi 1, 5, 6)
    bf* dst = Cb + (epi == 6 ? (size_t)blockIdx.z * M * N : 0);
    bf* my  = (bf*)(ldsS + wave * 2048);   // 4 KB per wave: [32][64] bf16

#pragma unroll
    for (int half = 0; half < 2; ++half) {
#pragma unroll
        for (int i2 = 0; i2 < 2; ++i2) {
            const int i = half * 2 + i2;
            const int gmb = bm0 + wm * 64 + i * 16 + quad * 4;
#pragma unroll
            for (int j = 0; j < 4; ++j) {
                const int gn = bn0 + wn * 64 + j * 16 + r16;
#pragma unroll
                for (int r = 0; r < 4; ++r) {
                    float val = acc[i][j][r];
                    if (epi == 1) {
                        val += bias[gn];
                        val = (val - bnm[gn]) * rsqrtf(bnv[gn] + EPS_BN) * bng[gn] + bnb[gn];
                        val = fmaxf(val, 0.f);
                    } else {
                        if (bias)  val += bias[gn];
                        if (biasm) val += biasm[gmb + r];
                    }
                    my[(i2 * 16 + quad * 4 + r) * 64 + j * 16 + r16] =
                        __float2bfloat16(val);
                }
            }
        }
#pragma unroll
        for (int it = 0; it < 4; ++it) {
            const int chunk = it * 64 + lane;
            const int lrow  = chunk >> 3;
            const int lcol  = (chunk & 7) * 8;
            const int grow  = bm0 + wm * 64 + half * 32 + lrow;
            const int gcol  = bn0 + wn * 64 + lcol;
            int4 v = *(const int4*)(my + lrow * 64 + lcol);
            *(int4*)(dst + (size_t)grow * N + gcol) = v;
        }
    }
}

// ---------------------------------------------------------------------------
// h2fuse: per 128-row tile of the 20480-row batch:
//   h1 = relu(A1*(Hp0+Hp1)+C1); h2 = relu(A2*(h1@W2^T)+C2)
//   q tiles  (r0<4096): qt = h2@Wqk^T -> qtb (h2 itself not needed in HBM)
//   bank tiles: h2 -> h2b, beta[n] = h2.vvec, transposed cols -> h2T
// ---------------------------------------------------------------------------
__global__ __launch_bounds__(256)
void h2fuse(const float* __restrict__ Hp,     // [2][MTOT][128] fp32 partials
            const bf* __restrict__ W2b,       // [128][128]
            const bf* __restrict__ Wqk,       // [128][128]
            const float* __restrict__ bnA,    // A1|C1|A2|C2 (4x128)
            const float* __restrict__ vvecP,  // [16][128]
            bf* __restrict__ h2b, bf* __restrict__ qtb,
            float* __restrict__ beta, bf* __restrict__ h2T)
{
    __shared__ __align__(16) short lsH[16384];   // [128][128] swizzled
    __shared__ __align__(16) short lsW[16384];   // [128][128] swizzled
    __shared__ float sA1[128], sC1[128], sA2[128], sC2[128];

    const int tid  = threadIdx.x;
    const int wave = tid >> 6;
    const int lane = tid & 63;
    const int r16  = lane & 15;
    const int quad = lane >> 4;
    const int wm   = wave >> 1;
    const int wn   = wave & 1;
    const int r0   = blockIdx.x * 128;
    const bool isq = (r0 < B_ROWS);

    // stage W2 (pre-swizzled global source -> linear LDS dest)
#pragma unroll
    for (int m = 0; m < 8; ++m) {
        const int s = m * 256 + tid;
        const int row = s >> 4, pcg = s & 15;
        load_lds16(W2b + row * 128 + (pcg ^ (row & 15)) * 8,
                   (char*)lsW + (m * 256 + wave * 64) * 16);
    }
    if (tid < 128) {
        sA1[tid] = bnA[tid];       sC1[tid] = bnA[128 + tid];
        sA2[tid] = bnA[256 + tid]; sC2[tid] = bnA[384 + tid];
    }
    __syncthreads();

    // h1 tile -> lsH (swizzled bf16)
#pragma unroll
    for (int m = 0; m < 16; ++m) {
        const int s = m * 256 + tid;
        const int row = s >> 5;
        const int col = (s & 31) * 4;
        const float* p0 = Hp + (size_t)(r0 + row) * 128 + col;
        float4 x0 = *(const float4*)p0;
        float4 x1 = *(const float4*)(p0 + (size_t)MTOT * 128);
        union { bf h[4]; int2 v; } u;
        u.h[0] = __float2bfloat16(fmaxf(fmaf(x0.x + x1.x, sA1[col],     sC1[col]),     0.f));
        u.h[1] = __float2bfloat16(fmaxf(fmaf(x0.y + x1.y, sA1[col + 1], sC1[col + 1]), 0.f));
        u.h[2] = __float2bfloat16(fmaxf(fmaf(x0.z + x1.z, sA1[col + 2], sC1[col + 2]), 0.f));
        u.h[3] = __float2bfloat16(fmaxf(fmaf(x0.w + x1.w, sA1[col + 3], sC1[col + 3]), 0.f));
        const int cg = col >> 3;
        *(int2*)((bf*)lsH + row * 128 + ((cg ^ (row & 15)) << 3) + (col & 7)) = u.v;
    }
    __syncthreads();   // lsH + lsW ready

    // pass 1: acc = h1 @ W2^T
    f32x4 acc[4][4];
#pragma unroll
    for (int i = 0; i < 4; ++i)
#pragma unroll
        for (int j = 0; j < 4; ++j) acc[i][j] = (f32x4){0.f, 0.f, 0.f, 0.f};
#pragma unroll
    for (int ks = 0; ks < 4; ++ks) {
        bf16x8 af[4], bfr[4];
#pragma unroll
        for (int i = 0; i < 4; ++i) {
            const int row = wm * 64 + i * 16 + r16;
            af[i] = *(const bf16x8*)(lsH + row * 128 + ((ks * 4 + quad) ^ (row & 15)) * 8);
        }
#pragma unroll
        for (int j = 0; j < 4; ++j) {
            const int row = wn * 64 + j * 16 + r16;
            bfr[j] = *(const bf16x8*)(lsW + row * 128 + ((ks * 4 + quad) ^ (row & 15)) * 8);
        }
#pragma unroll
        for (int i = 0; i < 4; ++i)
#pragma unroll
            for (int j = 0; j < 4; ++j)
                acc[i][j] = __builtin_amdgcn_mfma_f32_16x16x32_bf16(
                    af[i], bfr[j], acc[i][j], 0, 0, 0);
    }
    __syncthreads();   // pass-1 LDS reads complete

    if (isq) {
        // stage Wqk into lsW (dead after pass 1)
#pragma unroll
        for (int m = 0; m < 8; ++m) {
            const int s = m * 256 + tid;
            const int row = s >> 4, pcg = s & 15;
            load_lds16(Wqk + row * 128 + (pcg ^ (row & 15)) * 8,
                       (char*)lsW + (m * 256 + wave * 64) * 16);
        }
    }

    // epilogue: h2 = relu(A2*acc+C2) -> lsH (swizzled, overwrites h1)
#pragma unroll
    for (int i = 0; i < 4; ++i) {
#pragma unroll
        for (int j = 0; j < 4; ++j) {
            const int gn = wn * 64 + j * 16 + r16;
            const int cg = gn >> 3, cl = gn & 7;
            const float a2 = sA2[gn], c2 = sC2[gn];
#pragma unroll
            for (int r = 0; r < 4; ++r) {
                const int row = wm * 64 + i * 16 + quad * 4 + r;
                float v = fmaxf(fmaf(acc[i][j][r], a2, c2), 0.f);
                ((bf*)lsH)[row * 128 + ((cg ^ (row & 15)) << 3) + cl] =
                    __float2bfloat16(v);
            }
        }
    }
    __syncthreads();   // lsH(h2) visible; Wqk staging drained

    if (!isq) {
        // ---- bank tile: h2 -> h2b, beta, h2T columns ----
#pragma unroll
        for (int m = 0; m < 8; ++m) {
            const int s = m * 256 + tid;
            const int row = s >> 4, cg = s & 15;
            *(int4*)(h2b + (size_t)(r0 + row) * 128 + cg * 8) =
                *(const int4*)(lsH + row * 128 + ((cg ^ (row & 15)) << 3));
        }
        // vvec into sA1 (dead); barrier before cross-thread read
        if (tid < 128) {
            float s = 0.f;
#pragma unroll
            for (int z = 0; z < 16; ++z) s += vvecP[z * 128 + tid];
            sA1[tid] = s;
        }
        __syncthreads();
        const int nb0 = r0 - B_ROWS;
        // beta: 2 threads per row
        {
            const int row = tid >> 1, hf = tid & 1;
            float s = 0.f;
#pragma unroll
            for (int g = 0; g < 8; ++g) {
                const int cg = hf * 8 + g;
                bf16x8 v = *(const bf16x8*)(lsH + row * 128 + ((cg ^ (row & 15)) << 3));
#pragma unroll
                for (int e = 0; e < 8; ++e)
                    s += __bfloat162float((bf)v[e]) * sA1[cg * 8 + e];
            }
            s += __shfl_xor(s, 1, 64);
            if (hf == 0) beta[nb0 + row] = s;
        }
        // h2T: h2T[p][nb0+n] = h2[n][p]
#pragma unroll
        for (int m = 0; m < 8; ++m) {
            const int idx = m * 256 + tid;   // 0..2047
            const int p  = idx >> 4;
            const int ng = (idx & 15) * 8;
            union { bf h[8]; int4 v; } u;
#pragma unroll
            for (int e = 0; e < 8; ++e) {
                const int n = ng + e;
                u.h[e] = ((bf*)lsH)[n * 128 + (((p >> 3) ^ (n & 15)) << 3) + (p & 7)];
            }
            *(int4*)(h2T + (size_t)p * (2 * NBANK) + nb0 + ng) = u.v;
        }
        return;
    }

    // ---- q tile: pass 2: qt = h2 @ Wqk^T ----
    f32x4 acc2[4][4];
#pragma unroll
    for (int i = 0; i < 4; ++i)
#pragma unroll
        for (int j = 0; j < 4; ++j) acc2[i][j] = (f32x4){0.f, 0.f, 0.f, 0.f};
#pragma unroll
    for (int ks = 0; ks < 4; ++ks) {
        bf16x8 af[4], bfr[4];
#pragma unroll
        for (int i = 0; i < 4; ++i) {
            const int row = wm * 64 + i * 16 + r16;
            af[i] = *(const bf16x8*)(lsH + row * 128 + ((ks * 4 + quad) ^ (row & 15)) * 8);
        }
#pragma unroll
        for (int j = 0; j < 4; ++j) {
            const int row = wn * 64 + j * 16 + r16;
            bfr[j] = *(const bf16x8*)(lsW + row * 128 + ((ks * 4 + quad) ^ (row & 15)) * 8);
        }
#pragma unroll
        for (int i = 0; i < 4; ++i)
#pragma unroll
            for (int j = 0; j < 4; ++j)
                acc2[i][j] = __builtin_amdgcn_mfma_f32_16x16x32_bf16(
                    af[i], bfr[j], acc2[i][j], 0, 0, 0);
    }
    __syncthreads();   // lsW (Wqk) reads complete before my-region overwrite

    bf* my  = (bf*)lsW + wave * 2048;   // [32][64] per wave
    bf* dst = qtb + (size_t)r0 * 128;
#pragma unroll
    for (int half = 0; half < 2; ++half) {
#pragma unroll
        for (int i2 = 0; i2 < 2; ++i2) {
            const int i = half * 2 + i2;
#pragma unroll
            for (int j = 0; j < 4; ++j)
#pragma unroll
                for (int r = 0; r < 4; ++r)
                    my[(i2 * 16 + quad * 4 + r) * 64 + j * 16 + r16] =
                        __float2bfloat16(acc2[i][j][r]);
        }
#pragma unroll
        for (int it = 0; it < 4; ++it) {
            const int chunk = it * 64 + lane;
            const int lrow  = chunk >> 3;
            const int lcol  = (chunk & 7) * 8;
            const int grow  = wm * 64 + half * 32 + lrow;
            const int gcol  = wn * 64 + lcol;
            int4 v = *(const int4*)(my + lrow * 64 + lcol);
            *(int4*)(dst + (size_t)grow * 128 + gcol) = v;
        }
    }
}

// ---------------------------------------------------------------------------
// Fused attention v4: 32 q-rows per WAVE, 4 waves (256 thr), 48 KB LDS.
// R7's v3 spilled (launch_bounds(512,4) capped VGPR at 64 < the ~130 live
// state -> 231 MB scratch traffic). v4 keeps 32 rows/wave (halves LDS-read
// redundancy vs R6) but with 4 waves/block and NO min-waves hint: VGPR ~135
// -> 3 waves/SIMD, 3 blocks/CU by LDS (48 KB).
// ---------------------------------------------------------------------------
__global__ __launch_bounds__(256)
void attn_fused(const bf* __restrict__ qt,      // [4096][128]
                const bf* __restrict__ h2bank,  // [16384][128] side-major
                const bf* __restrict__ h2T,     // [128][16384]
                const float* __restrict__ beta, // [16384]
                bf* __restrict__ Ypart,         // [32][4096][128]
                float* __restrict__ rsP)        // [32][4096]
{
    __shared__ __align__(16) short lds[24576];   // 48 KB -> 3 blocks/CU
    short* lsK = lds;            // [64][128],  phys cg = cg ^ (row&15)
    short* lsV = lds + 8192;     // [128][64],  phys cg = cg ^ (row&7)
    short* lsS = lds + 16384;    // [128][64],  phys cg = cg ^ (row&7)

    const int tid  = threadIdx.x;
    const int wave = tid >> 6;
    const int lane = tid & 63;
    const int r16  = lane & 15;
    const int quad = lane >> 4;

    const int qb   = blockIdx.x >> 5;          // 32 q-blocks of 128 rows
    const int side = (blockIdx.x >> 4) & 1;
    const int seg  = blockIdx.x & 15;
    const int part = side * KVSEG + seg;
    const int nseg0 = seg * (NBANK / KVSEG);
    const bf* kbase = h2bank + (size_t)side * NBANK * P_DIM;
    const int ncol0 = side * NBANK;
    const int q0 = qb * 128 + wave * 32;

    // Q fragments in registers (wave-private 32 q-rows, loop-invariant)
    bf16x8 qreg[2][4];
#pragma unroll
    for (int i = 0; i < 2; ++i) {
        const bf* qrow = qt + (size_t)(q0 + i * 16 + r16) * P_DIM;
#pragma unroll
        for (int ks = 0; ks < 4; ++ks)
            qreg[i][ks] = *(const bf16x8*)(qrow + (ks * 4 + quad) * 8);
    }

    f32x4 yacc[2][8];
    float rsacc[2][4] = {{0.f,0.f,0.f,0.f},{0.f,0.f,0.f,0.f}};
#pragma unroll
    for (int i = 0; i < 2; ++i)
#pragma unroll
        for (int j = 0; j < 8; ++j) yacc[i][j] = (f32x4){0.f, 0.f, 0.f, 0.f};

    for (int c = 0; c < CHUNKS; ++c) {
        const int kv0 = nseg0 + c * KCH;
        __syncthreads();   // prev chunk's lsK/lsV reads done -> safe to restage
        // stage K chunk [64][128]
#pragma unroll
        for (int m = 0; m < 4; ++m) {
            const int s = m * 256 + tid;
            const int row = s >> 4, pcg = s & 15;
            const int lcg = pcg ^ (row & 15);
            load_lds16(kbase + (size_t)(kv0 + row) * P_DIM + lcg * 8,
                       (char*)lsK + (m * 256 + wave * 64) * 16);
        }
        // stage V chunk [128][64] from h2T
#pragma unroll
        for (int m = 0; m < 4; ++m) {
            const int s = m * 256 + tid;
            const int row = s >> 3, pcg = s & 7;
            const int lcg = pcg ^ (row & 7);
            load_lds16(h2T + (size_t)row * (2 * NBANK) + ncol0 + kv0 + lcg * 8,
                       (char*)lsV + (m * 256 + wave * 64) * 16);
        }
        __syncthreads();   // staging complete

        // QK + exp per 16-row group (i-sequential: sacc stays at 16 VGPR)
#pragma unroll
        for (int i = 0; i < 2; ++i) {
            f32x4 sacc[4];
#pragma unroll
            for (int j = 0; j < 4; ++j) sacc[j] = (f32x4){0.f, 0.f, 0.f, 0.f};
#pragma unroll
            for (int ks = 0; ks < 4; ++ks)
#pragma unroll
                for (int j = 0; j < 4; ++j) {
                    const int kr = j * 16 + r16;
                    bf16x8 bfr = *(const bf16x8*)(lsK + kr * 128 +
                                                  ((ks * 4 + quad) ^ (kr & 15)) * 8);
                    sacc[j] = __builtin_amdgcn_mfma_f32_16x16x32_bf16(
                        qreg[i][ks], bfr, sacc[j], 0, 0, 0);
                }
            // exp -> lsS (wave-private rows; no barrier needed before PV)
#pragma unroll
            for (int j = 0; j < 4; ++j) {
                const int col = j * 16 + r16;
                const float bv = beta[(size_t)side * NBANK + kv0 + col];
                const int cg = col >> 3, cl = col & 7;
#pragma unroll
                for (int r = 0; r < 4; ++r) {
                    const int row = wave * 32 + i * 16 + quad * 4 + r;
                    float v = __expf(SCALE_S * (sacc[j][r] + bv));
                    rsacc[i][r] += v;
                    ((bf*)lsS)[row * 64 + ((cg ^ (row & 7)) << 3) + cl] =
                        __float2bfloat16(v);
                }
            }
        }

        // PV: Y[32][128] += S[32][64] @ V (pb shared across both row groups)
#pragma unroll
        for (int ks = 0; ks < 2; ++ks) {
            const int sr0 = wave * 32 + r16, sr1 = sr0 + 16;
            bf16x8 pa0 = *(const bf16x8*)(lsS + sr0 * 64 +
                                          ((ks * 4 + quad) ^ (sr0 & 7)) * 8);
            bf16x8 pa1 = *(const bf16x8*)(lsS + sr1 * 64 +
                                          ((ks * 4 + quad) ^ (sr1 & 7)) * 8);
#pragma unroll
            for (int j = 0; j < 8; ++j) {
                const int vr = j * 16 + r16;
                bf16x8 pb = *(const bf16x8*)(lsV + vr * 64 +
                                             ((ks * 4 + quad) ^ (vr & 7)) * 8);
                yacc[0][j] = __builtin_amdgcn_mfma_f32_16x16x32_bf16(
                    pa0, pb, yacc[0][j], 0, 0, 0);
                yacc[1][j] = __builtin_amdgcn_mfma_f32_16x16x32_bf16(
                    pa1, pb, yacc[1][j], 0, 0, 0);
            }
        }
    }

    // rowsum partials: reduce across the 16-lane r16 group; rows wave-private
#pragma unroll
    for (int i = 0; i < 2; ++i) {
#pragma unroll
        for (int r = 0; r < 4; ++r) {
            float s = rsacc[i][r];
            s += __shfl_xor(s, 1, 64);
            s += __shfl_xor(s, 2, 64);
            s += __shfl_xor(s, 4, 64);
            s += __shfl_xor(s, 8, 64);
            rsacc[i][r] = s;
        }
        if (r16 == 0)
            *(float4*)(rsP + (size_t)part * B_ROWS + q0 + i * 16 + quad * 4) =
                (float4){rsacc[i][0], rsacc[i][1], rsacc[i][2], rsacc[i][3]};
    }

    // Y partial store via per-wave LDS staging (whole LDS dead after barrier)
    __syncthreads();
    bf* my = (bf*)lds + wave * 4096;   // [32][128] bf16 = 8 KB per wave
#pragma unroll
    for (int i = 0; i < 2; ++i)
#pragma unroll
        for (int j = 0; j < 8; ++j)
#pragma unroll
            for (int r = 0; r < 4; ++r)
                my[(i * 16 + quad * 4 + r) * 128 + j * 16 + r16] =
                    __float2bfloat16(yacc[i][j][r]);
    bf* dst = Ypart + (size_t)part * B_ROWS * P_DIM + (size_t)q0 * P_DIM;
#pragma unroll
    for (int it = 0; it < 8; ++it) {
        const int chunk = it * 64 + lane;       // 0..511 int4s
        const int lrow  = chunk >> 4;
        const int lcol  = (chunk & 15) * 8;
        *(int4*)(dst + (size_t)lrow * P_DIM + lcol) =
            *(const int4*)(my + lrow * 128 + lcol);
    }
}

// ---------------------------------------------------------------------------
// prep mega-kernel: all input-only transforms in ONE dispatch (range-split).
// ---------------------------------------------------------------------------
#define PG0 10240   // convX
#define PG1 584     // convW
#define PG2 64      // convW3T
#define PG3 512     // ftpad
#define PG4 8       // vvecP partials
#define PG5 256     // bvp
#define PG6 1       // folded BN coefficients A1|C1|A2|C2

__global__ __launch_bounds__(256)
void prep(const float* __restrict__ Fv, const float* __restrict__ Fvs,
          const float* __restrict__ Fvt,
          const float* __restrict__ W1, const float* __restrict__ W2,
          const float* __restrict__ Wp,
          const float* __restrict__ W3, const float* __restrict__ b3,
          const float* __restrict__ bp, const float* __restrict__ Ft,
          const float* __restrict__ b1, const float* __restrict__ g1,
          const float* __restrict__ be1, const float* __restrict__ m1,
          const float* __restrict__ v1,
          const float* __restrict__ b2, const float* __restrict__ g2,
          const float* __restrict__ be2, const float* __restrict__ m2,
          const float* __restrict__ v2,
          bf* __restrict__ Xb, bf* __restrict__ W1b, bf* __restrict__ W2b,
          bf* __restrict__ Wpb,
          bf* __restrict__ Tq, bf* __restrict__ Tk, bf* __restrict__ Tv,
          bf* __restrict__ Ftb,
          float* __restrict__ vvecP, float* __restrict__ bvp,
          float* __restrict__ bnA)
{
    const int tid = threadIdx.x;
    int b = blockIdx.x;
    if (b < PG0) {                       // ---- convX: Fv|Fvs|Fvt -> bf16
        int i = (b * 256 + tid) * 8;
        const int n0 = B_ROWS * D_DIM, n1 = n0 + NBANK * D_DIM;
        const float* src; int off;
        if (i < n0)      { src = Fv;  off = i; }
        else if (i < n1) { src = Fvs; off = i - n0; }
        else             { src = Fvt; off = i - n1; }
        float4 a = *(const float4*)(src + off);
        float4 c = *(const float4*)(src + off + 4);
        *(int4*)(Xb + i) = pack8(a, c);
        return;
    }
    if ((b -= PG0) < PG1) {              // ---- convW: W1|W2|Wp -> bf16
        int i = (b * 256 + tid) * 8;
        const int n1 = P_DIM * D_DIM, n2 = n1 + P_DIM * P_DIM;
        const float* src; bf* dst; int off;
        if (i < n1)      { src = W1; dst = W1b; off = i; }
        else if (i < n2) { src = W2; dst = W2b; off = i - n1; }
        else             { src = Wp; dst = Wpb; off = i - n2; }
        float4 a = *(const float4*)(src + off);
        float4 c = *(const float4*)(src + off + 4);
        *(int4*)(dst + off) = pack8(a, c);
        return;
    }
    if ((b -= PG1) < PG2) {              // ---- convW3T: Txx[p,d] = W3[3d+x,p]
        int i = (b * 256 + tid) * 8;
        int p = i >> 10, d0 = i & 1023;
        union { bf h[8]; int4 v; } uq, uk, uv;
#pragma unroll
        for (int j = 0; j < 8; ++j) {
            const float* r = W3 + (size_t)3 * (d0 + j) * P_DIM + p;
            uq.h[j] = __float2bfloat16(r[0]);
            uk.h[j] = __float2bfloat16(r[P_DIM]);
            uv.h[j] = __float2bfloat16(r[2 * P_DIM]);
        }
        *(int4*)(Tq + i) = uq.v;
        *(int4*)(Tk + i) = uk.v;
        *(int4*)(Tv + i) = uv.v;
        return;
    }
    if ((b -= PG2) < PG3) {              // ---- ftpad
        int i = (b * 256 + tid) * 8;
        int row = i >> 10, col = i & 1023;
        if (row < C_CLS) {
            float4 a = *(const float4*)(Ft + (size_t)row * D_DIM + col);
            float4 c = *(const float4*)(Ft + (size_t)row * D_DIM + col + 4);
            *(int4*)(Ftb + i) = pack8(a, c);
        } else {
            *(int4*)(Ftb + i) = (int4){0, 0, 0, 0};
        }
        return;
    }
    if ((b -= PG3) < PG4) {              // ---- vvecP partials of W3k^T b3q
        const int p = tid & 127, hf = tid >> 7;
        const int dbase = b * 128 + hf * 64;
        float s = 0.f;
        for (int dd = 0; dd < 64; ++dd) {
            const int d = dbase + dd;
            s = fmaf(b3[3 * d], W3[(size_t)(3 * d + 1) * P_DIM + p], s);
        }
        vvecP[(b * 2 + hf) * P_DIM + p] = s;
        return;
    }
    if ((b -= PG4) < PG5) {              // ---- bvp[o] = Wp[o,:].b3v + bp[o]
        const int wave = tid >> 6, lane = tid & 63;
        const int o = b * 4 + wave;
        const float* r = Wp + (size_t)o * D_DIM;
        float s = 0.f;
        for (int i = lane; i < D_DIM; i += 64) s = fmaf(r[i], b3[3 * i + 2], s);
        for (int off = 32; off > 0; off >>= 1) s += __shfl_down(s, off, 64);
        if (lane == 0) bvp[o] = s + bp[o];
        return;
    }
    // ---- folded BN coefficients
    if (tid < 128) {
        float a1 = g1[tid] * rsqrtf(v1[tid] + EPS_BN);
        bnA[tid]       = a1;
        bnA[128 + tid] = (b1[tid] - m1[tid]) * a1 + be1[tid];
        float a2 = g2[tid] * rsqrtf(v2[tid] + EPS_BN);
        bnA[256 + tid] = a2;
        bnA[384 + tid] = (b2[tid] - m2[tid]) * a2 + be2[tid];
    }
}

// fused reduce for the merged weight-fold GEMM: WWp = [8][1152][128] bf16;
// rows 0-127 of each part -> Wqk, rows 128-1151 -> Wpv.
__global__ __launch_bounds__(256)
void reduceWW(const bf* __restrict__ WWp,
              bf* __restrict__ Wqk, bf* __restrict__ Wpv)
{
    const int tid = threadIdx.x;
    const size_t pstride = (size_t)1152 * 128;
    if (blockIdx.x < 8) {
        int i = (blockIdx.x * 256 + tid) * 8;          // < 16384
        float s[8] = {};
        for (int z = 0; z < 8; ++z) {
            union { int4 v; bf h[8]; } u;
            u.v = *(const int4*)(WWp + (size_t)z * pstride + i);
#pragma unroll
            for (int e = 0; e < 8; ++e) s[e] += __bfloat162float(u.h[e]);
        }
        union { bf h[8]; int4 v; } o;
#pragma unroll
        for (int e = 0; e < 8; ++e) o.h[e] = __float2bfloat16(s[e]);
        *(int4*)(Wqk + i) = o.v;
    } else {
        int i = ((blockIdx.x - 8) * 256 + tid) * 8;    // < 131072
        float s[8] = {};
        for (int z = 0; z < 8; ++z) {
            union { int4 v; bf h[8]; } u;
            u.v = *(const int4*)(WWp + (size_t)z * pstride + 16384 + i);
#pragma unroll
            for (int e = 0; e < 8; ++e) s[e] += __bfloat162float(u.h[e]);
        }
        union { bf h[8]; int4 v; } o;
#pragma unroll
        for (int e = 0; e < 8; ++e) o.h[e] = __float2bfloat16(s[e]);
        *(int4*)(Wpv + i) = o.v;
    }
}

// reduceY: Yhat[s][b][p] = sum_z parts[s*16+z][b][p] / (sum_g rsP[s*16+g][b])
__global__ __launch_bounds__(256)
void reduceY(const bf* __restrict__ parts, const float* __restrict__ rsP,
             bf* __restrict__ Yhat)
{
    int j = (blockIdx.x * 256 + threadIdx.x) * 8;      // < 2*B_ROWS*P_DIM
    const int s = j >> 19;                             // B_ROWS*P_DIM = 2^19
    const int qrow = (j >> 7) & (B_ROWS - 1);
    float rs = 0.f;
#pragma unroll
    for (int g = 0; g < KVSEG; ++g)
        rs += rsP[(size_t)(s * KVSEG + g) * B_ROWS + qrow];
    const bf* p = parts + (size_t)s * KVSEG * 524288 + (size_t)(j & 524287);
    float acc[8] = {};
    for (int z = 0; z < KVSEG; ++z) {
        union { int4 v; bf h[8]; } u;
        u.v = *(const int4*)(p + (size_t)z * 524288);
#pragma unroll
        for (int e = 0; e < 8; ++e) acc[e] += __bfloat162float(u.h[e]);
    }
    const float inv = 1.0f / rs;
    union { bf h[8]; int4 v; } o;
#pragma unroll
    for (int e = 0; e < 8; ++e) o.h[e] = __float2bfloat16(acc[e] * inv);
    *(int4*)(Yhat + j) = o.v;
}

// dual row L2-normalize + bf16 out
__global__ __launch_bounds__(256)
void rownorm2b(const float* __restrict__ G, bf* __restrict__ out)
{
    __shared__ float red[16];
    const int tid = threadIdx.x;
    const float* ps = G + (size_t)blockIdx.x * D_DIM;
    const float* pt = ps + (size_t)B_ROWS * D_DIM;
    float4 a = *(const float4*)(ps + tid * 4);
    float4 c = *(const float4*)(pt + tid * 4);
    float sa = a.x * a.x + a.y * a.y + a.z * a.z + a.w * a.w;
    float sb = c.x * c.x + c.y * c.y + c.z * c.z + c.w * c.w;
    for (int s = 32; s > 0; s >>= 1) {
        sa += __shfl_down(sa, s, 64);
        sb += __shfl_down(sb, s, 64);
    }
    if ((tid & 63) == 0) { red[tid >> 6] = sa; red[8 + (tid >> 6)] = sb; }
    __syncthreads();
    if (tid == 0) {
        float ta = 0.f, tb = 0.f;
        for (int w = 0; w < 4; ++w) { ta += red[w]; tb += red[8 + w]; }
        red[4] = rsqrtf(ta); red[12] = rsqrtf(tb);
    }
    __syncthreads();
    const float ia = red[4], ib = red[12];
    union { bf h[4]; int2 v; } o;
    o.h[0] = __float2bfloat16(a.x * ia + c.x * ib);
    o.h[1] = __float2bfloat16(a.y * ia + c.y * ib);
    o.h[2] = __float2bfloat16(a.z * ia + c.z * ib);
    o.h[3] = __float2bfloat16(a.w * ia + c.w * ib);
    *(int2*)(out + (size_t)blockIdx.x * D_DIM + tid * 4) = o.v;
}

// ---------------------------------------------------------------------------
// R8: fix R7's VGPR-spill regression (launch_bounds(512,4) -> 64-VGPR cap ->
// 231 MB scratch). attn_fused v4: 4 waves x 32 rows/wave, 48 KB LDS, no
// min-waves hint. Rest identical to R7.
// ---------------------------------------------------------------------------
extern "C" void kernel_launch(void* const* d_in, const int* in_sizes, int n_in,
                              void* d_out, int out_size, void* d_ws, size_t ws_size,
                              hipStream_t stream)
{
    (void)in_sizes; (void)n_in; (void)out_size; (void)ws_size;

    const float* Ft  = (const float*)d_in[0];
    const float* Fv  = (const float*)d_in[1];
    const float* Fvs = (const float*)d_in[2];
    const float* Fvt = (const float*)d_in[3];
    const float* W1  = (const float*)d_in[4];
    const float* b1  = (const float*)d_in[5];
    const float* g1  = (const float*)d_in[6];
    const float* be1 = (const float*)d_in[7];
    const float* m1  = (const float*)d_in[8];
    const float* v1  = (const float*)d_in[9];
    const float* W2  = (const float*)d_in[10];
    const float* b2  = (const float*)d_in[11];
    const float* g2  = (const float*)d_in[12];
    const float* be2 = (const float*)d_in[13];
    const float* m2  = (const float*)d_in[14];
    const float* v2  = (const float*)d_in[15];
    const float* W3  = (const float*)d_in[16];
    const float* b3  = (const float*)d_in[17];
    const float* Wp  = (const float*)d_in[18];
    const float* bp  = (const float*)d_in[19];
    const float* ls  = (const float*)d_in[20];

    char* base = (char*)d_ws;
    size_t o = 0;
    auto take = [&](size_t s) { size_t r = o; o += (s + 255) & ~(size_t)255; return r; };

    // persistent (~25 MB). NOTE: W3kT and Wpb MUST be contiguous (merged fold
    // GEMM treats them as one 1152-row A matrix; sizes are 256B-multiples).
    bf* qtb   = (bf*)(base + take((size_t)B_ROWS * P_DIM * 2));
    bf* h2T   = (bf*)(base + take((size_t)P_DIM * 2 * NBANK * 2));
    bf* Yhat  = (bf*)(base + take((size_t)2 * B_ROWS * P_DIM * 2));
    bf* Ftb   = (bf*)(base + take((size_t)D_DIM * D_DIM * 2));
    bf* W3qT  = (bf*)(base + take((size_t)P_DIM * D_DIM * 2));
    bf* W3kT  = (bf*)(base + take((size_t)P_DIM * D_DIM * 2));
    bf* Wpb   = (bf*)(base + take((size_t)D_DIM * D_DIM * 2));   // after W3kT!
    bf* W3vT  = (bf*)(base + take((size_t)P_DIM * D_DIM * 2));
    bf* Wqk   = (bf*)(base + take((size_t)P_DIM * P_DIM * 2));
    bf* Wpvb  = (bf*)(base + take((size_t)D_DIM * P_DIM * 2));
    bf* W1b   = (bf*)(base + take((size_t)P_DIM * D_DIM * 2));
    bf* W2b   = (bf*)(base + take((size_t)P_DIM * P_DIM * 2));
    bf* h2b   = (bf*)(base + take((size_t)MTOT * P_DIM * 2));
    bf* WWp   = (bf*)(base + take((size_t)8 * 1152 * P_DIM * 2));
    float* vvecP = (float*)(base + take((size_t)16 * P_DIM * 4));
    float* beta  = (float*)(base + take((size_t)2 * NBANK * 4));
    float* bvp   = (float*)(base + take(D_DIM * 4));
    float* bnA   = (float*)(base + take(4 * P_DIM * 4));
    float* rsP   = (float*)(base + take((size_t)2 * KVSEG * B_ROWS * 4));

    // scratch region (aliased across phases)
    const size_t Dbase = o;
    bf*    Xb    = (bf*)(base + Dbase);                                  // 40 MB
    float* Hp    = (float*)(base + Dbase + (size_t)MTOT * D_DIM * 2);    // 21 MB
    bf*    Opart = (bf*)(base + Dbase + (size_t)64 * 1024 * 1024);       // 32 MB
    float* G     = (float*)(base + Dbase);                               // 32 MB
    bf*    Fsumb = (bf*)(base + Dbase + (size_t)2 * B_ROWS * D_DIM * 4); // 8 MB

    auto gemm = [&](const bf* A, const bf* B, const bf* B2,
                    int M, int N, int K, int lda, int ldb,
                    int kch, int fx, int fy, int epi, float* Cf, bf* Cb,
                    const float* bias, const float* biasm,
                    const float* bg, const float* bb, const float* bm, const float* bv,
                    const float* addsrc, const float* lsp, int ldc) {
        gemm_bf16<<<dim3(N / 128, M / 128, kch), dim3(256), 0, stream>>>(
            A, B, B2, M, N, K, lda, ldb, kch, fx, fy, epi, Cf, Cb, bias, biasm,
            bg, bb, bm, bv, addsrc, lsp, ldc);
    };

    // 1) prep: all input-only transforms + folded BN coefficients
    prep<<<dim3(PG0 + PG1 + PG2 + PG3 + PG4 + PG5 + PG6), dim3(256), 0, stream>>>(
        Fv, Fvs, Fvt, W1, W2, Wp, W3, b3, bp, Ft,
        b1, g1, be1, m1, v1, b2, g2, be2, m2, v2,
        Xb, W1b, W2b, Wpb, W3qT, W3kT, W3vT, Ftb, vvecP, bvp, bnA);

    // 2) merged weight folds: A = [W3kT; Wpb] (1152 rows), B tile 0 = W3qT
    //    (-> Wqk rows), tiles 1-8 = W3vT (-> Wpv rows); split-K 8.
    gemm(W3kT, W3qT, W3vT, 1152, P_DIM, D_DIM, D_DIM, D_DIM, 8, 0, 0, 6,
         nullptr, WWp, nullptr, nullptr, nullptr, nullptr, nullptr, nullptr,
         nullptr, nullptr, 0);
    // 3) fused reduces
    reduceWW<<<dim3(72), dim3(256), 0, stream>>>(WWp, Wqk, Wpvb);

    // 4) pre_project GEMM1, split-K fp32 partials (epi 8)
    gemm(Xb, W1b, nullptr, MTOT, P_DIM, D_DIM, D_DIM, D_DIM, 2, 1, 8, 8,
         Hp, nullptr, nullptr, nullptr, nullptr, nullptr, nullptr, nullptr,
         nullptr, nullptr, 0);
    // 5) h2fuse: partial-sum + BN1/ReLU + GEMM2 + BN2/ReLU + {Qtilde | beta,h2T}
    h2fuse<<<dim3(MTOT / 128), dim3(256), 0, stream>>>(
        Hp, W2b, Wqk, bnA, vvecP, h2b, qtb, beta, h2T);

    // 6) fused attention: S in LDS only; Y/rowsum seg partials
    attn_fused<<<dim3(2 * KVSEG * (B_ROWS / 128)), dim3(256), 0, stream>>>(
        qtb, h2b + (size_t)B_ROWS * P_DIM, h2T, beta, Opart, rsP);
    // 7) fold segments + softmax normalize -> Yhat [2*B_ROWS,128]
    reduceY<<<dim3(2 * B_ROWS * P_DIM / 2048), dim3(256), 0, stream>>>(
        Opart, rsP, Yhat);

    // 8) combined post-project (K=128) + residual
    gemm(Yhat, Wpvb, nullptr, 2 * B_ROWS, D_DIM, P_DIM, P_DIM, P_DIM, 1, 1, 8, 3,
         G, nullptr, bvp, nullptr, nullptr, nullptr, nullptr, nullptr, Fv,
         nullptr, B_ROWS);
    // 9) dual rownorm -> bf16
    rownorm2b<<<dim3(B_ROWS), dim3(256), 0, stream>>>(G, Fsumb);
    // 10) logits
    gemm(Fsumb, Ftb, nullptr, B_ROWS, D_DIM, D_DIM, D_DIM, D_DIM, 1, 1, 8, 4,
         (float*)d_out, nullptr, nullptr, nullptr, nullptr, nullptr, nullptr,
         nullptr, nullptr, ls, C_CLS);
}

// Round 9
// 328.398 us; speedup vs baseline: 1.2674x; 1.1435x over previous
//
#include <hip/hip_runtime.h>
#include <hip/hip_bf16.h>
#include <math.h>

#define D_DIM   1024
#define P_DIM   128
#define B_ROWS  4096
#define NBANK   8192
#define C_CLS   1000
#define EPS_BN  1e-5f
#define SCALE_S 0.1f
#define MTOT    20480   // 4096 + 8192 + 8192 batched pre_project rows
#define KVSEG   16      // kv segments per side (softmax split)
#define KCH     64      // kv rows per fused chunk
#define CHUNKS  (NBANK / KVSEG / KCH)   // 8

typedef __bf16 bf16x8 __attribute__((ext_vector_type(8)));
typedef float  f32x4  __attribute__((ext_vector_type(4)));
typedef __hip_bfloat16 bf;

__device__ __forceinline__ void load_lds16(const void* gp, void* lp) {
    __builtin_amdgcn_global_load_lds(
        (__attribute__((address_space(1))) void*)gp,
        (__attribute__((address_space(3))) void*)lp, 16, 0, 0);
}

__device__ __forceinline__ int4 pack8(float4 a, float4 b) {
    union { bf h[8]; int4 v; } u;
    u.h[0] = __float2bfloat16(a.x); u.h[1] = __float2bfloat16(a.y);
    u.h[2] = __float2bfloat16(a.z); u.h[3] = __float2bfloat16(a.w);
    u.h[4] = __float2bfloat16(b.x); u.h[5] = __float2bfloat16(b.y);
    u.h[6] = __float2bfloat16(b.z); u.h[7] = __float2bfloat16(b.w);
    return u.v;
}

// ---------------------------------------------------------------------------
// bf16 MFMA GEMM: C[M,N] = A[M,K] @ B[N,K]^T (row-major bf16), 128x128 tile.
// A row stride = lda; B row stride = ldb. kchunks>1 -> split-K via blockIdx.z.
// fx==0 -> identity block map (no XCD remap); B2 != null -> M-tiles with
// by>0 use B2 instead of B (merged weight-fold dispatch).
// epi: 1 +bias,BN,ReLU -> bf16 | 3 fp32 +bias + addsrc[(gm&(ldc-1))*N+gn] |
//      4 fp32 *exp(*lsp), cols<ldc | 5 bf16 (+bias[n], +biasm[m]) |
//      6 bf16 partial at Cb + z*M*N | 8 fp32 plain partial at Cf + z*M*N
// ---------------------------------------------------------------------------
__global__ __launch_bounds__(256)
void gemm_bf16(const bf* __restrict__ A, const bf* __restrict__ B,
               const bf* __restrict__ B2,
               int M, int N, int K, int lda, int ldb,
               int kchunks, int fx, int fy, int epi,
               float* __restrict__ Cf, bf* __restrict__ Cb,
               const float* __restrict__ bias, const float* __restrict__ biasm,
               const float* __restrict__ bng, const float* __restrict__ bnb,
               const float* __restrict__ bnm, const float* __restrict__ bnv,
               const float* __restrict__ addsrc, const float* __restrict__ lsp,
               int ldc)
{
    __shared__ __align__(16) short ldsS[8192];   // 16 KB
    short* lsA = ldsS;          // [128][32]
    short* lsB = ldsS + 4096;   // [128][32]

    const int tid  = threadIdx.x;
    const int wave = tid >> 6;
    const int lane = tid & 63;
    const int wm   = wave >> 1;
    const int wn   = wave & 1;
    const int r16  = lane & 15;
    const int quad = lane >> 4;

    // XCD-aware tile remap (fx==0 -> identity)
    int bx, by;
    if (fx == 0) {
        bx = blockIdx.x; by = blockIdx.y;
    } else {
        const int gx = gridDim.x, gy = gridDim.y;
        const int l   = blockIdx.y * gx + blockIdx.x;
        const int xcd = l & 7;
        const int i0  = l >> 3;
        const int sx  = gx / fx, sy = gy / fy;
        bx = (xcd % fx) * sx + (i0 % sx);
        by = (xcd / fx) * sy + (i0 / sx);
    }
    const int bm0 = by * 128;
    const int bn0 = bx * 128;
    const bf* Bp = (B2 && by > 0) ? B2 : B;

    const int kper = K / kchunks;
    const int kbeg = blockIdx.z * kper;
    const int kend = kbeg + kper;

    f32x4 acc[4][4];
#pragma unroll
    for (int i = 0; i < 4; ++i)
#pragma unroll
        for (int j = 0; j < 4; ++j) acc[i][j] = (f32x4){0.f, 0.f, 0.f, 0.f};

    for (int k0 = kbeg; k0 < kend; k0 += 32) {
#pragma unroll
        for (int i = 0; i < 2; ++i) {
            const int s   = i * 256 + tid;
            const int row = s >> 2;
            const int cc  = (s & 3) * 8;
            const int lofs = (i * 256 + wave * 64) * 16;
            load_lds16(A + (size_t)(bm0 + row) * lda + k0 + cc, (char*)lsA + lofs);
            load_lds16(Bp + (size_t)(bn0 + row) * ldb + k0 + cc, (char*)lsB + lofs);
        }
        __syncthreads();

        bf16x8 af[4], bfr[4];
#pragma unroll
        for (int i = 0; i < 4; ++i)
            af[i] = *(const bf16x8*)(lsA + (wm * 64 + i * 16 + r16) * 32 + quad * 8);
#pragma unroll
        for (int j = 0; j < 4; ++j)
            bfr[j] = *(const bf16x8*)(lsB + (wn * 64 + j * 16 + r16) * 32 + quad * 8);
#pragma unroll
        for (int i = 0; i < 4; ++i)
#pragma unroll
            for (int j = 0; j < 4; ++j)
                acc[i][j] = __builtin_amdgcn_mfma_f32_16x16x32_bf16(
                    af[i], bfr[j], acc[i][j], 0, 0, 0);
        __syncthreads();
    }

    if (epi == 8) {
        float* dst = Cf + (size_t)blockIdx.z * M * N;
#pragma unroll
        for (int i = 0; i < 4; ++i) {
            const int gmb = bm0 + wm * 64 + i * 16 + quad * 4;
#pragma unroll
            for (int j = 0; j < 4; ++j) {
                const int gn = bn0 + wn * 64 + j * 16 + r16;
#pragma unroll
                for (int r = 0; r < 4; ++r)
                    dst[(size_t)(gmb + r) * N + gn] = acc[i][j][r];
            }
        }
        return;
    }

    if (epi == 3 || epi == 4) {
        const float lsv = (epi == 4) ? expf(*lsp) : 1.0f;
#pragma unroll
        for (int i = 0; i < 4; ++i) {
            const int gmb = bm0 + wm * 64 + i * 16 + quad * 4;
#pragma unroll
            for (int j = 0; j < 4; ++j) {
                const int gn = bn0 + wn * 64 + j * 16 + r16;
#pragma unroll
                for (int r = 0; r < 4; ++r) {
                    const int gm = gmb + r;
                    float val = acc[i][j][r];
                    if (epi == 3) {
                        Cf[(size_t)gm * N + gn] =
                            val + bias[gn] + addsrc[(size_t)(gm & (ldc - 1)) * N + gn];
                    } else {
                        if (gn < ldc) Cf[(size_t)gm * ldc + gn] = val * lsv;
                    }
                }
            }
        }
        return;
    }

    // bf16 LDS-staged store path (epi 1, 5, 6)
    bf* dst = Cb + (epi == 6 ? (size_t)blockIdx.z * M * N : 0);
    bf* my  = (bf*)(ldsS + wave * 2048);   // 4 KB per wave: [32][64] bf16

#pragma unroll
    for (int half = 0; half < 2; ++half) {
#pragma unroll
        for (int i2 = 0; i2 < 2; ++i2) {
            const int i = half * 2 + i2;
            const int gmb = bm0 + wm * 64 + i * 16 + quad * 4;
#pragma unroll
            for (int j = 0; j < 4; ++j) {
                const int gn = bn0 + wn * 64 + j * 16 + r16;
#pragma unroll
                for (int r = 0; r < 4; ++r) {
                    float val = acc[i][j][r];
                    if (epi == 1) {
                        val += bias[gn];
                        val = (val - bnm[gn]) * rsqrtf(bnv[gn] + EPS_BN) * bng[gn] + bnb[gn];
                        val = fmaxf(val, 0.f);
                    } else {
                        if (bias)  val += bias[gn];
                        if (biasm) val += biasm[gmb + r];
                    }
                    my[(i2 * 16 + quad * 4 + r) * 64 + j * 16 + r16] =
                        __float2bfloat16(val);
                }
            }
        }
#pragma unroll
        for (int it = 0; it < 4; ++it) {
            const int chunk = it * 64 + lane;
            const int lrow  = chunk >> 3;
            const int lcol  = (chunk & 7) * 8;
            const int grow  = bm0 + wm * 64 + half * 32 + lrow;
            const int gcol  = bn0 + wn * 64 + lcol;
            int4 v = *(const int4*)(my + lrow * 64 + lcol);
            *(int4*)(dst + (size_t)grow * N + gcol) = v;
        }
    }
}

// ---------------------------------------------------------------------------
// h2fuse: per 128-row tile of the 20480-row batch:
//   h1 = relu(A1*(Hp0+Hp1)+C1); h2 = relu(A2*(h1@W2^T)+C2)
//   q tiles  (r0<4096): qt = h2@Wqk^T -> qtb (h2 itself not needed in HBM)
//   bank tiles: h2 -> h2b, beta[n] = h2.vvec, transposed cols -> h2T
// ---------------------------------------------------------------------------
__global__ __launch_bounds__(256)
void h2fuse(const float* __restrict__ Hp,     // [2][MTOT][128] fp32 partials
            const bf* __restrict__ W2b,       // [128][128]
            const bf* __restrict__ Wqk,       // [128][128]
            const float* __restrict__ bnA,    // A1|C1|A2|C2 (4x128)
            const float* __restrict__ vvecP,  // [16][128]
            bf* __restrict__ h2b, bf* __restrict__ qtb,
            float* __restrict__ beta, bf* __restrict__ h2T)
{
    __shared__ __align__(16) short lsH[16384];   // [128][128] swizzled
    __shared__ __align__(16) short lsW[16384];   // [128][128] swizzled
    __shared__ float sA1[128], sC1[128], sA2[128], sC2[128];

    const int tid  = threadIdx.x;
    const int wave = tid >> 6;
    const int lane = tid & 63;
    const int r16  = lane & 15;
    const int quad = lane >> 4;
    const int wm   = wave >> 1;
    const int wn   = wave & 1;
    const int r0   = blockIdx.x * 128;
    const bool isq = (r0 < B_ROWS);

    // stage W2 (pre-swizzled global source -> linear LDS dest)
#pragma unroll
    for (int m = 0; m < 8; ++m) {
        const int s = m * 256 + tid;
        const int row = s >> 4, pcg = s & 15;
        load_lds16(W2b + row * 128 + (pcg ^ (row & 15)) * 8,
                   (char*)lsW + (m * 256 + wave * 64) * 16);
    }
    if (tid < 128) {
        sA1[tid] = bnA[tid];       sC1[tid] = bnA[128 + tid];
        sA2[tid] = bnA[256 + tid]; sC2[tid] = bnA[384 + tid];
    }
    __syncthreads();

    // h1 tile -> lsH (swizzled bf16)
#pragma unroll
    for (int m = 0; m < 16; ++m) {
        const int s = m * 256 + tid;
        const int row = s >> 5;
        const int col = (s & 31) * 4;
        const float* p0 = Hp + (size_t)(r0 + row) * 128 + col;
        float4 x0 = *(const float4*)p0;
        float4 x1 = *(const float4*)(p0 + (size_t)MTOT * 128);
        union { bf h[4]; int2 v; } u;
        u.h[0] = __float2bfloat16(fmaxf(fmaf(x0.x + x1.x, sA1[col],     sC1[col]),     0.f));
        u.h[1] = __float2bfloat16(fmaxf(fmaf(x0.y + x1.y, sA1[col + 1], sC1[col + 1]), 0.f));
        u.h[2] = __float2bfloat16(fmaxf(fmaf(x0.z + x1.z, sA1[col + 2], sC1[col + 2]), 0.f));
        u.h[3] = __float2bfloat16(fmaxf(fmaf(x0.w + x1.w, sA1[col + 3], sC1[col + 3]), 0.f));
        const int cg = col >> 3;
        *(int2*)((bf*)lsH + row * 128 + ((cg ^ (row & 15)) << 3) + (col & 7)) = u.v;
    }
    __syncthreads();   // lsH + lsW ready

    // pass 1: acc = h1 @ W2^T
    f32x4 acc[4][4];
#pragma unroll
    for (int i = 0; i < 4; ++i)
#pragma unroll
        for (int j = 0; j < 4; ++j) acc[i][j] = (f32x4){0.f, 0.f, 0.f, 0.f};
#pragma unroll
    for (int ks = 0; ks < 4; ++ks) {
        bf16x8 af[4], bfr[4];
#pragma unroll
        for (int i = 0; i < 4; ++i) {
            const int row = wm * 64 + i * 16 + r16;
            af[i] = *(const bf16x8*)(lsH + row * 128 + ((ks * 4 + quad) ^ (row & 15)) * 8);
        }
#pragma unroll
        for (int j = 0; j < 4; ++j) {
            const int row = wn * 64 + j * 16 + r16;
            bfr[j] = *(const bf16x8*)(lsW + row * 128 + ((ks * 4 + quad) ^ (row & 15)) * 8);
        }
#pragma unroll
        for (int i = 0; i < 4; ++i)
#pragma unroll
            for (int j = 0; j < 4; ++j)
                acc[i][j] = __builtin_amdgcn_mfma_f32_16x16x32_bf16(
                    af[i], bfr[j], acc[i][j], 0, 0, 0);
    }
    __syncthreads();   // pass-1 LDS reads complete

    if (isq) {
        // stage Wqk into lsW (dead after pass 1)
#pragma unroll
        for (int m = 0; m < 8; ++m) {
            const int s = m * 256 + tid;
            const int row = s >> 4, pcg = s & 15;
            load_lds16(Wqk + row * 128 + (pcg ^ (row & 15)) * 8,
                       (char*)lsW + (m * 256 + wave * 64) * 16);
        }
    }

    // epilogue: h2 = relu(A2*acc+C2) -> lsH (swizzled, overwrites h1)
#pragma unroll
    for (int i = 0; i < 4; ++i) {
#pragma unroll
        for (int j = 0; j < 4; ++j) {
            const int gn = wn * 64 + j * 16 + r16;
            const int cg = gn >> 3, cl = gn & 7;
            const float a2 = sA2[gn], c2 = sC2[gn];
#pragma unroll
            for (int r = 0; r < 4; ++r) {
                const int row = wm * 64 + i * 16 + quad * 4 + r;
                float v = fmaxf(fmaf(acc[i][j][r], a2, c2), 0.f);
                ((bf*)lsH)[row * 128 + ((cg ^ (row & 15)) << 3) + cl] =
                    __float2bfloat16(v);
            }
        }
    }
    __syncthreads();   // lsH(h2) visible; Wqk staging drained

    if (!isq) {
        // ---- bank tile: h2 -> h2b, beta, h2T columns ----
#pragma unroll
        for (int m = 0; m < 8; ++m) {
            const int s = m * 256 + tid;
            const int row = s >> 4, cg = s & 15;
            *(int4*)(h2b + (size_t)(r0 + row) * 128 + cg * 8) =
                *(const int4*)(lsH + row * 128 + ((cg ^ (row & 15)) << 3));
        }
        // vvec into sA1 (dead); barrier before cross-thread read
        if (tid < 128) {
            float s = 0.f;
#pragma unroll
            for (int z = 0; z < 16; ++z) s += vvecP[z * 128 + tid];
            sA1[tid] = s;
        }
        __syncthreads();
        const int nb0 = r0 - B_ROWS;
        // beta: 2 threads per row
        {
            const int row = tid >> 1, hf = tid & 1;
            float s = 0.f;
#pragma unroll
            for (int g = 0; g < 8; ++g) {
                const int cg = hf * 8 + g;
                bf16x8 v = *(const bf16x8*)(lsH + row * 128 + ((cg ^ (row & 15)) << 3));
#pragma unroll
                for (int e = 0; e < 8; ++e)
                    s += __bfloat162float((bf)v[e]) * sA1[cg * 8 + e];
            }
            s += __shfl_xor(s, 1, 64);
            if (hf == 0) beta[nb0 + row] = s;
        }
        // h2T: h2T[p][nb0+n] = h2[n][p]
#pragma unroll
        for (int m = 0; m < 8; ++m) {
            const int idx = m * 256 + tid;   // 0..2047
            const int p  = idx >> 4;
            const int ng = (idx & 15) * 8;
            union { bf h[8]; int4 v; } u;
#pragma unroll
            for (int e = 0; e < 8; ++e) {
                const int n = ng + e;
                u.h[e] = ((bf*)lsH)[n * 128 + (((p >> 3) ^ (n & 15)) << 3) + (p & 7)];
            }
            *(int4*)(h2T + (size_t)p * (2 * NBANK) + nb0 + ng) = u.v;
        }
        return;
    }

    // ---- q tile: pass 2: qt = h2 @ Wqk^T ----
    f32x4 acc2[4][4];
#pragma unroll
    for (int i = 0; i < 4; ++i)
#pragma unroll
        for (int j = 0; j < 4; ++j) acc2[i][j] = (f32x4){0.f, 0.f, 0.f, 0.f};
#pragma unroll
    for (int ks = 0; ks < 4; ++ks) {
        bf16x8 af[4], bfr[4];
#pragma unroll
        for (int i = 0; i < 4; ++i) {
            const int row = wm * 64 + i * 16 + r16;
            af[i] = *(const bf16x8*)(lsH + row * 128 + ((ks * 4 + quad) ^ (row & 15)) * 8);
        }
#pragma unroll
        for (int j = 0; j < 4; ++j) {
            const int row = wn * 64 + j * 16 + r16;
            bfr[j] = *(const bf16x8*)(lsW + row * 128 + ((ks * 4 + quad) ^ (row & 15)) * 8);
        }
#pragma unroll
        for (int i = 0; i < 4; ++i)
#pragma unroll
            for (int j = 0; j < 4; ++j)
                acc2[i][j] = __builtin_amdgcn_mfma_f32_16x16x32_bf16(
                    af[i], bfr[j], acc2[i][j], 0, 0, 0);
    }
    __syncthreads();   // lsW (Wqk) reads complete before my-region overwrite

    bf* my  = (bf*)lsW + wave * 2048;   // [32][64] per wave
    bf* dst = qtb + (size_t)r0 * 128;
#pragma unroll
    for (int half = 0; half < 2; ++half) {
#pragma unroll
        for (int i2 = 0; i2 < 2; ++i2) {
            const int i = half * 2 + i2;
#pragma unroll
            for (int j = 0; j < 4; ++j)
#pragma unroll
                for (int r = 0; r < 4; ++r)
                    my[(i2 * 16 + quad * 4 + r) * 64 + j * 16 + r16] =
                        __float2bfloat16(acc2[i][j][r]);
        }
#pragma unroll
        for (int it = 0; it < 4; ++it) {
            const int chunk = it * 64 + lane;
            const int lrow  = chunk >> 3;
            const int lcol  = (chunk & 7) * 8;
            const int grow  = wm * 64 + half * 32 + lrow;
            const int gcol  = wn * 64 + lcol;
            int4 v = *(const int4*)(my + lrow * 64 + lcol);
            *(int4*)(dst + (size_t)grow * 128 + gcol) = v;
        }
    }
}

// ---------------------------------------------------------------------------
// Fused attention (R6-v2, proven 55 µs): 8 waves x 16 q-rows, 48 KB LDS,
// VGPR ~64+64 -> ~3 blocks/CU. R7/R8's 32-rows/wave variants both failed on
// the register wall (yacc alone = 64 VGPR/lane at 32 rows -> spill or 1
// wave/SIMD). S rows are wave-private: no barrier between exp-write and
// PV-read; 2 barriers/chunk. + T5 setprio around MFMA clusters (m191: +4-7%
// on attn with independent blocks per CU).
// ---------------------------------------------------------------------------
__global__ __launch_bounds__(512)
void attn_fused(const bf* __restrict__ qt,      // [4096][128]
                const bf* __restrict__ h2bank,  // [16384][128] side-major
                const bf* __restrict__ h2T,     // [128][16384]
                const float* __restrict__ beta, // [16384]
                bf* __restrict__ Ypart,         // [32][4096][128]
                float* __restrict__ rsP)        // [32][4096]
{
    __shared__ __align__(16) short lds[24576];   // 48 KB
    short* lsK = lds;            // [64][128],  phys cg = cg ^ (row&15)
    short* lsV = lds + 8192;     // [128][64],  phys cg = cg ^ (row&7)
    short* lsS = lds + 16384;    // [128][64],  phys cg = cg ^ (row&7)

    const int tid  = threadIdx.x;
    const int wave = tid >> 6;
    const int lane = tid & 63;
    const int r16  = lane & 15;
    const int quad = lane >> 4;

    const int qb   = blockIdx.x >> 5;
    const int side = (blockIdx.x >> 4) & 1;
    const int seg  = blockIdx.x & 15;
    const int part = side * KVSEG + seg;
    const int nseg0 = seg * (NBANK / KVSEG);
    const bf* kbase = h2bank + (size_t)side * NBANK * P_DIM;
    const int ncol0 = side * NBANK;

    const bf* qrow = qt + (size_t)(qb * 128 + wave * 16 + r16) * P_DIM;
    bf16x8 qreg[4];
#pragma unroll
    for (int ks = 0; ks < 4; ++ks)
        qreg[ks] = *(const bf16x8*)(qrow + (ks * 4 + quad) * 8);

    f32x4 yacc[8];
    float rsacc[4] = {0.f, 0.f, 0.f, 0.f};
#pragma unroll
    for (int j = 0; j < 8; ++j) yacc[j] = (f32x4){0.f, 0.f, 0.f, 0.f};

    for (int c = 0; c < CHUNKS; ++c) {
        const int kv0 = nseg0 + c * KCH;
        __syncthreads();
#pragma unroll
        for (int m = 0; m < 2; ++m) {
            const int s = m * 512 + tid;
            const int row = s >> 4, pcg = s & 15;
            const int lcg = pcg ^ (row & 15);
            load_lds16(kbase + (size_t)(kv0 + row) * P_DIM + lcg * 8,
                       (char*)lsK + (m * 512 + wave * 64) * 16);
        }
#pragma unroll
        for (int m = 0; m < 2; ++m) {
            const int s = m * 512 + tid;
            const int row = s >> 3, pcg = s & 7;
            const int lcg = pcg ^ (row & 7);
            load_lds16(h2T + (size_t)row * (2 * NBANK) + ncol0 + kv0 + lcg * 8,
                       (char*)lsV + (m * 512 + wave * 64) * 16);
        }
        __syncthreads();

        f32x4 sacc[4];
#pragma unroll
        for (int j = 0; j < 4; ++j) sacc[j] = (f32x4){0.f, 0.f, 0.f, 0.f};
        __builtin_amdgcn_s_setprio(1);
#pragma unroll
        for (int ks = 0; ks < 4; ++ks) {
            bf16x8 bfr[4];
#pragma unroll
            for (int j = 0; j < 4; ++j) {
                const int kr = j * 16 + r16;
                bfr[j] = *(const bf16x8*)(lsK + kr * 128 +
                                          ((ks * 4 + quad) ^ (kr & 15)) * 8);
            }
#pragma unroll
            for (int j = 0; j < 4; ++j)
                sacc[j] = __builtin_amdgcn_mfma_f32_16x16x32_bf16(
                    qreg[ks], bfr[j], sacc[j], 0, 0, 0);
        }
        __builtin_amdgcn_s_setprio(0);

#pragma unroll
        for (int j = 0; j < 4; ++j) {
            const int col = j * 16 + r16;
            const float bv = beta[(size_t)side * NBANK + kv0 + col];
            const int cg = col >> 3, cl = col & 7;
#pragma unroll
            for (int r = 0; r < 4; ++r) {
                const int row = wave * 16 + quad * 4 + r;
                float v = __expf(SCALE_S * (sacc[j][r] + bv));
                rsacc[r] += v;
                ((bf*)lsS)[row * 64 + ((cg ^ (row & 7)) << 3) + cl] =
                    __float2bfloat16(v);
            }
        }

        __builtin_amdgcn_s_setprio(1);
#pragma unroll
        for (int ks = 0; ks < 2; ++ks) {
            const int sr = wave * 16 + r16;
            bf16x8 pa = *(const bf16x8*)(lsS + sr * 64 +
                                         ((ks * 4 + quad) ^ (sr & 7)) * 8);
            bf16x8 pb[8];
#pragma unroll
            for (int j = 0; j < 8; ++j) {
                const int vr = j * 16 + r16;
                pb[j] = *(const bf16x8*)(lsV + vr * 64 +
                                         ((ks * 4 + quad) ^ (vr & 7)) * 8);
            }
#pragma unroll
            for (int j = 0; j < 8; ++j)
                yacc[j] = __builtin_amdgcn_mfma_f32_16x16x32_bf16(
                    pa, pb[j], yacc[j], 0, 0, 0);
        }
        __builtin_amdgcn_s_setprio(0);
    }

#pragma unroll
    for (int r = 0; r < 4; ++r) {
        float s = rsacc[r];
        s += __shfl_xor(s, 1, 64);
        s += __shfl_xor(s, 2, 64);
        s += __shfl_xor(s, 4, 64);
        s += __shfl_xor(s, 8, 64);
        rsacc[r] = s;
    }
    if (r16 == 0)
        *(float4*)(rsP + (size_t)part * B_ROWS + qb * 128 + wave * 16 + quad * 4) =
            (float4){rsacc[0], rsacc[1], rsacc[2], rsacc[3]};

    __syncthreads();
    bf* my = (bf*)lds + wave * 2048;   // [16][128] bf16 = 4 KB per wave
#pragma unroll
    for (int j = 0; j < 8; ++j)
#pragma unroll
        for (int r = 0; r < 4; ++r)
            my[(quad * 4 + r) * 128 + j * 16 + r16] =
                __float2bfloat16(yacc[j][r]);
    bf* dst = Ypart + (size_t)part * B_ROWS * P_DIM
                    + (size_t)(qb * 128 + wave * 16) * P_DIM;
#pragma unroll
    for (int it = 0; it < 4; ++it) {
        const int chunk = it * 64 + lane;       // 0..255 int4s
        const int lrow  = chunk >> 4;
        const int lcol  = (chunk & 15) * 8;
        *(int4*)(dst + (size_t)lrow * P_DIM + lcol) =
            *(const int4*)(my + lrow * 128 + lcol);
    }
}

// ---------------------------------------------------------------------------
// prep mega-kernel: all input-only transforms in ONE dispatch (range-split).
// ---------------------------------------------------------------------------
#define PG0 10240   // convX
#define PG1 584     // convW
#define PG2 64      // convW3T
#define PG3 512     // ftpad
#define PG4 8       // vvecP partials
#define PG5 256     // bvp
#define PG6 1       // folded BN coefficients A1|C1|A2|C2

__global__ __launch_bounds__(256)
void prep(const float* __restrict__ Fv, const float* __restrict__ Fvs,
          const float* __restrict__ Fvt,
          const float* __restrict__ W1, const float* __restrict__ W2,
          const float* __restrict__ Wp,
          const float* __restrict__ W3, const float* __restrict__ b3,
          const float* __restrict__ bp, const float* __restrict__ Ft,
          const float* __restrict__ b1, const float* __restrict__ g1,
          const float* __restrict__ be1, const float* __restrict__ m1,
          const float* __restrict__ v1,
          const float* __restrict__ b2, const float* __restrict__ g2,
          const float* __restrict__ be2, const float* __restrict__ m2,
          const float* __restrict__ v2,
          bf* __restrict__ Xb, bf* __restrict__ W1b, bf* __restrict__ W2b,
          bf* __restrict__ Wpb,
          bf* __restrict__ Tq, bf* __restrict__ Tk, bf* __restrict__ Tv,
          bf* __restrict__ Ftb,
          float* __restrict__ vvecP, float* __restrict__ bvp,
          float* __restrict__ bnA)
{
    const int tid = threadIdx.x;
    int b = blockIdx.x;
    if (b < PG0) {                       // ---- convX: Fv|Fvs|Fvt -> bf16
        int i = (b * 256 + tid) * 8;
        const int n0 = B_ROWS * D_DIM, n1 = n0 + NBANK * D_DIM;
        const float* src; int off;
        if (i < n0)      { src = Fv;  off = i; }
        else if (i < n1) { src = Fvs; off = i - n0; }
        else             { src = Fvt; off = i - n1; }
        float4 a = *(const float4*)(src + off);
        float4 c = *(const float4*)(src + off + 4);
        *(int4*)(Xb + i) = pack8(a, c);
        return;
    }
    if ((b -= PG0) < PG1) {              // ---- convW: W1|W2|Wp -> bf16
        int i = (b * 256 + tid) * 8;
        const int n1 = P_DIM * D_DIM, n2 = n1 + P_DIM * P_DIM;
        const float* src; bf* dst; int off;
        if (i < n1)      { src = W1; dst = W1b; off = i; }
        else if (i < n2) { src = W2; dst = W2b; off = i - n1; }
        else             { src = Wp; dst = Wpb; off = i - n2; }
        float4 a = *(const float4*)(src + off);
        float4 c = *(const float4*)(src + off + 4);
        *(int4*)(dst + off) = pack8(a, c);
        return;
    }
    if ((b -= PG1) < PG2) {              // ---- convW3T: Txx[p,d] = W3[3d+x,p]
        int i = (b * 256 + tid) * 8;
        int p = i >> 10, d0 = i & 1023;
        union { bf h[8]; int4 v; } uq, uk, uv;
#pragma unroll
        for (int j = 0; j < 8; ++j) {
            const float* r = W3 + (size_t)3 * (d0 + j) * P_DIM + p;
            uq.h[j] = __float2bfloat16(r[0]);
            uk.h[j] = __float2bfloat16(r[P_DIM]);
            uv.h[j] = __float2bfloat16(r[2 * P_DIM]);
        }
        *(int4*)(Tq + i) = uq.v;
        *(int4*)(Tk + i) = uk.v;
        *(int4*)(Tv + i) = uv.v;
        return;
    }
    if ((b -= PG2) < PG3) {              // ---- ftpad
        int i = (b * 256 + tid) * 8;
        int row = i >> 10, col = i & 1023;
        if (row < C_CLS) {
            float4 a = *(const float4*)(Ft + (size_t)row * D_DIM + col);
            float4 c = *(const float4*)(Ft + (size_t)row * D_DIM + col + 4);
            *(int4*)(Ftb + i) = pack8(a, c);
        } else {
            *(int4*)(Ftb + i) = (int4){0, 0, 0, 0};
        }
        return;
    }
    if ((b -= PG3) < PG4) {              // ---- vvecP partials of W3k^T b3q
        const int p = tid & 127, hf = tid >> 7;
        const int dbase = b * 128 + hf * 64;
        float s = 0.f;
        for (int dd = 0; dd < 64; ++dd) {
            const int d = dbase + dd;
            s = fmaf(b3[3 * d], W3[(size_t)(3 * d + 1) * P_DIM + p], s);
        }
        vvecP[(b * 2 + hf) * P_DIM + p] = s;
        return;
    }
    if ((b -= PG4) < PG5) {              // ---- bvp[o] = Wp[o,:].b3v + bp[o]
        const int wave = tid >> 6, lane = tid & 63;
        const int o = b * 4 + wave;
        const float* r = Wp + (size_t)o * D_DIM;
        float s = 0.f;
        for (int i = lane; i < D_DIM; i += 64) s = fmaf(r[i], b3[3 * i + 2], s);
        for (int off = 32; off > 0; off >>= 1) s += __shfl_down(s, off, 64);
        if (lane == 0) bvp[o] = s + bp[o];
        return;
    }
    // ---- folded BN coefficients
    if (tid < 128) {
        float a1 = g1[tid] * rsqrtf(v1[tid] + EPS_BN);
        bnA[tid]       = a1;
        bnA[128 + tid] = (b1[tid] - m1[tid]) * a1 + be1[tid];
        float a2 = g2[tid] * rsqrtf(v2[tid] + EPS_BN);
        bnA[256 + tid] = a2;
        bnA[384 + tid] = (b2[tid] - m2[tid]) * a2 + be2[tid];
    }
}

// fused reduce for the merged weight-fold GEMM: WWp = [8][1152][128] bf16;
// rows 0-127 of each part -> Wqk, rows 128-1151 -> Wpv.
__global__ __launch_bounds__(256)
void reduceWW(const bf* __restrict__ WWp,
              bf* __restrict__ Wqk, bf* __restrict__ Wpv)
{
    const int tid = threadIdx.x;
    const size_t pstride = (size_t)1152 * 128;
    if (blockIdx.x < 8) {
        int i = (blockIdx.x * 256 + tid) * 8;          // < 16384
        float s[8] = {};
        for (int z = 0; z < 8; ++z) {
            union { int4 v; bf h[8]; } u;
            u.v = *(const int4*)(WWp + (size_t)z * pstride + i);
#pragma unroll
            for (int e = 0; e < 8; ++e) s[e] += __bfloat162float(u.h[e]);
        }
        union { bf h[8]; int4 v; } o;
#pragma unroll
        for (int e = 0; e < 8; ++e) o.h[e] = __float2bfloat16(s[e]);
        *(int4*)(Wqk + i) = o.v;
    } else {
        int i = ((blockIdx.x - 8) * 256 + tid) * 8;    // < 131072
        float s[8] = {};
        for (int z = 0; z < 8; ++z) {
            union { int4 v; bf h[8]; } u;
            u.v = *(const int4*)(WWp + (size_t)z * pstride + 16384 + i);
#pragma unroll
            for (int e = 0; e < 8; ++e) s[e] += __bfloat162float(u.h[e]);
        }
        union { bf h[8]; int4 v; } o;
#pragma unroll
        for (int e = 0; e < 8; ++e) o.h[e] = __float2bfloat16(s[e]);
        *(int4*)(Wpv + i) = o.v;
    }
}

// reduceY: Yhat[s][b][p] = sum_z parts[s*16+z][b][p] / (sum_g rsP[s*16+g][b])
__global__ __launch_bounds__(256)
void reduceY(const bf* __restrict__ parts, const float* __restrict__ rsP,
             bf* __restrict__ Yhat)
{
    int j = (blockIdx.x * 256 + threadIdx.x) * 8;      // < 2*B_ROWS*P_DIM
    const int s = j >> 19;                             // B_ROWS*P_DIM = 2^19
    const int qrow = (j >> 7) & (B_ROWS - 1);
    float rs = 0.f;
#pragma unroll
    for (int g = 0; g < KVSEG; ++g)
        rs += rsP[(size_t)(s * KVSEG + g) * B_ROWS + qrow];
    const bf* p = parts + (size_t)s * KVSEG * 524288 + (size_t)(j & 524287);
    float acc[8] = {};
    for (int z = 0; z < KVSEG; ++z) {
        union { int4 v; bf h[8]; } u;
        u.v = *(const int4*)(p + (size_t)z * 524288);
#pragma unroll
        for (int e = 0; e < 8; ++e) acc[e] += __bfloat162float(u.h[e]);
    }
    const float inv = 1.0f / rs;
    union { bf h[8]; int4 v; } o;
#pragma unroll
    for (int e = 0; e < 8; ++e) o.h[e] = __float2bfloat16(acc[e] * inv);
    *(int4*)(Yhat + j) = o.v;
}

// dual row L2-normalize + bf16 out
__global__ __launch_bounds__(256)
void rownorm2b(const float* __restrict__ G, bf* __restrict__ out)
{
    __shared__ float red[16];
    const int tid = threadIdx.x;
    const float* ps = G + (size_t)blockIdx.x * D_DIM;
    const float* pt = ps + (size_t)B_ROWS * D_DIM;
    float4 a = *(const float4*)(ps + tid * 4);
    float4 c = *(const float4*)(pt + tid * 4);
    float sa = a.x * a.x + a.y * a.y + a.z * a.z + a.w * a.w;
    float sb = c.x * c.x + c.y * c.y + c.z * c.z + c.w * c.w;
    for (int s = 32; s > 0; s >>= 1) {
        sa += __shfl_down(sa, s, 64);
        sb += __shfl_down(sb, s, 64);
    }
    if ((tid & 63) == 0) { red[tid >> 6] = sa; red[8 + (tid >> 6)] = sb; }
    __syncthreads();
    if (tid == 0) {
        float ta = 0.f, tb = 0.f;
        for (int w = 0; w < 4; ++w) { ta += red[w]; tb += red[8 + w]; }
        red[4] = rsqrtf(ta); red[12] = rsqrtf(tb);
    }
    __syncthreads();
    const float ia = red[4], ib = red[12];
    union { bf h[4]; int2 v; } o;
    o.h[0] = __float2bfloat16(a.x * ia + c.x * ib);
    o.h[1] = __float2bfloat16(a.y * ia + c.y * ib);
    o.h[2] = __float2bfloat16(a.z * ia + c.z * ib);
    o.h[3] = __float2bfloat16(a.w * ia + c.w * ib);
    *(int2*)(out + (size_t)blockIdx.x * D_DIM + tid * 4) = o.v;
}

// ---------------------------------------------------------------------------
// R9: revert attn_fused to R6's proven v2 (16 rows/wave, 8 waves, 64+64 regs
// -> 3 blocks/CU; both 32-rows/wave attempts hit the register wall). Keep all
// R7/R8 non-attn wins (merged folds, h2fuse+beta/h2T, split-K GEMM1). Add T5
// setprio around attn MFMA clusters.
// ---------------------------------------------------------------------------
extern "C" void kernel_launch(void* const* d_in, const int* in_sizes, int n_in,
                              void* d_out, int out_size, void* d_ws, size_t ws_size,
                              hipStream_t stream)
{
    (void)in_sizes; (void)n_in; (void)out_size; (void)ws_size;

    const float* Ft  = (const float*)d_in[0];
    const float* Fv  = (const float*)d_in[1];
    const float* Fvs = (const float*)d_in[2];
    const float* Fvt = (const float*)d_in[3];
    const float* W1  = (const float*)d_in[4];
    const float* b1  = (const float*)d_in[5];
    const float* g1  = (const float*)d_in[6];
    const float* be1 = (const float*)d_in[7];
    const float* m1  = (const float*)d_in[8];
    const float* v1  = (const float*)d_in[9];
    const float* W2  = (const float*)d_in[10];
    const float* b2  = (const float*)d_in[11];
    const float* g2  = (const float*)d_in[12];
    const float* be2 = (const float*)d_in[13];
    const float* m2  = (const float*)d_in[14];
    const float* v2  = (const float*)d_in[15];
    const float* W3  = (const float*)d_in[16];
    const float* b3  = (const float*)d_in[17];
    const float* Wp  = (const float*)d_in[18];
    const float* bp  = (const float*)d_in[19];
    const float* ls  = (const float*)d_in[20];

    char* base = (char*)d_ws;
    size_t o = 0;
    auto take = [&](size_t s) { size_t r = o; o += (s + 255) & ~(size_t)255; return r; };

    // persistent (~25 MB). NOTE: W3kT and Wpb MUST be contiguous (merged fold
    // GEMM treats them as one 1152-row A matrix; sizes are 256B-multiples).
    bf* qtb   = (bf*)(base + take((size_t)B_ROWS * P_DIM * 2));
    bf* h2T   = (bf*)(base + take((size_t)P_DIM * 2 * NBANK * 2));
    bf* Yhat  = (bf*)(base + take((size_t)2 * B_ROWS * P_DIM * 2));
    bf* Ftb   = (bf*)(base + take((size_t)D_DIM * D_DIM * 2));
    bf* W3qT  = (bf*)(base + take((size_t)P_DIM * D_DIM * 2));
    bf* W3kT  = (bf*)(base + take((size_t)P_DIM * D_DIM * 2));
    bf* Wpb   = (bf*)(base + take((size_t)D_DIM * D_DIM * 2));   // after W3kT!
    bf* W3vT  = (bf*)(base + take((size_t)P_DIM * D_DIM * 2));
    bf* Wqk   = (bf*)(base + take((size_t)P_DIM * P_DIM * 2));
    bf* Wpvb  = (bf*)(base + take((size_t)D_DIM * P_DIM * 2));
    bf* W1b   = (bf*)(base + take((size_t)P_DIM * D_DIM * 2));
    bf* W2b   = (bf*)(base + take((size_t)P_DIM * P_DIM * 2));
    bf* h2b   = (bf*)(base + take((size_t)MTOT * P_DIM * 2));
    bf* WWp   = (bf*)(base + take((size_t)8 * 1152 * P_DIM * 2));
    float* vvecP = (float*)(base + take((size_t)16 * P_DIM * 4));
    float* beta  = (float*)(base + take((size_t)2 * NBANK * 4));
    float* bvp   = (float*)(base + take(D_DIM * 4));
    float* bnA   = (float*)(base + take(4 * P_DIM * 4));
    float* rsP   = (float*)(base + take((size_t)2 * KVSEG * B_ROWS * 4));

    // scratch region (aliased across phases)
    const size_t Dbase = o;
    bf*    Xb    = (bf*)(base + Dbase);                                  // 40 MB
    float* Hp    = (float*)(base + Dbase + (size_t)MTOT * D_DIM * 2);    // 21 MB
    bf*    Opart = (bf*)(base + Dbase + (size_t)64 * 1024 * 1024);       // 32 MB
    float* G     = (float*)(base + Dbase);                               // 32 MB
    bf*    Fsumb = (bf*)(base + Dbase + (size_t)2 * B_ROWS * D_DIM * 4); // 8 MB

    auto gemm = [&](const bf* A, const bf* B, const bf* B2,
                    int M, int N, int K, int lda, int ldb,
                    int kch, int fx, int fy, int epi, float* Cf, bf* Cb,
                    const float* bias, const float* biasm,
                    const float* bg, const float* bb, const float* bm, const float* bv,
                    const float* addsrc, const float* lsp, int ldc) {
        gemm_bf16<<<dim3(N / 128, M / 128, kch), dim3(256), 0, stream>>>(
            A, B, B2, M, N, K, lda, ldb, kch, fx, fy, epi, Cf, Cb, bias, biasm,
            bg, bb, bm, bv, addsrc, lsp, ldc);
    };

    // 1) prep: all input-only transforms + folded BN coefficients
    prep<<<dim3(PG0 + PG1 + PG2 + PG3 + PG4 + PG5 + PG6), dim3(256), 0, stream>>>(
        Fv, Fvs, Fvt, W1, W2, Wp, W3, b3, bp, Ft,
        b1, g1, be1, m1, v1, b2, g2, be2, m2, v2,
        Xb, W1b, W2b, Wpb, W3qT, W3kT, W3vT, Ftb, vvecP, bvp, bnA);

    // 2) merged weight folds: A = [W3kT; Wpb] (1152 rows), B tile 0 = W3qT
    //    (-> Wqk rows), tiles 1-8 = W3vT (-> Wpv rows); split-K 8.
    gemm(W3kT, W3qT, W3vT, 1152, P_DIM, D_DIM, D_DIM, D_DIM, 8, 0, 0, 6,
         nullptr, WWp, nullptr, nullptr, nullptr, nullptr, nullptr, nullptr,
         nullptr, nullptr, 0);
    // 3) fused reduces
    reduceWW<<<dim3(72), dim3(256), 0, stream>>>(WWp, Wqk, Wpvb);

    // 4) pre_project GEMM1, split-K fp32 partials (epi 8)
    gemm(Xb, W1b, nullptr, MTOT, P_DIM, D_DIM, D_DIM, D_DIM, 2, 1, 8, 8,
         Hp, nullptr, nullptr, nullptr, nullptr, nullptr, nullptr, nullptr,
         nullptr, nullptr, 0);
    // 5) h2fuse: partial-sum + BN1/ReLU + GEMM2 + BN2/ReLU + {Qtilde | beta,h2T}
    h2fuse<<<dim3(MTOT / 128), dim3(256), 0, stream>>>(
        Hp, W2b, Wqk, bnA, vvecP, h2b, qtb, beta, h2T);

    // 6) fused attention: S in LDS only; Y/rowsum seg partials
    attn_fused<<<dim3(2 * KVSEG * (B_ROWS / 128)), dim3(512), 0, stream>>>(
        qtb, h2b + (size_t)B_ROWS * P_DIM, h2T, beta, Opart, rsP);
    // 7) fold segments + softmax normalize -> Yhat [2*B_ROWS,128]
    reduceY<<<dim3(2 * B_ROWS * P_DIM / 2048), dim3(256), 0, stream>>>(
        Opart, rsP, Yhat);

    // 8) combined post-project (K=128) + residual
    gemm(Yhat, Wpvb, nullptr, 2 * B_ROWS, D_DIM, P_DIM, P_DIM, P_DIM, 1, 1, 8, 3,
         G, nullptr, bvp, nullptr, nullptr, nullptr, nullptr, nullptr, Fv,
         nullptr, B_ROWS);
    // 9) dual rownorm -> bf16
    rownorm2b<<<dim3(B_ROWS), dim3(256), 0, stream>>>(G, Fsumb);
    // 10) logits
    gemm(Fsumb, Ftb, nullptr, B_ROWS, D_DIM, D_DIM, D_DIM, D_DIM, 1, 1, 8, 4,
         (float*)d_out, nullptr, nullptr, nullptr, nullptr, nullptr, nullptr,
         nullptr, nullptr, ls, C_CLS);
}

// Round 10
// 326.930 us; speedup vs baseline: 1.2731x; 1.0045x over previous
//
#include <hip/hip_runtime.h>
#include <hip/hip_bf16.h>
#include <math.h>

#define D_DIM   1024
#define P_DIM   128
#define B_ROWS  4096
#define NBANK   8192
#define C_CLS   1000
#define EPS_BN  1e-5f
#define SCALE_S 0.1f
#define MTOT    20480   // 4096 + 8192 + 8192 batched pre_project rows
#define KVSEG   16      // kv segments per side (softmax split)
#define KCH     64      // kv rows per fused chunk
#define CHUNKS  (NBANK / KVSEG / KCH)   // 8

typedef __bf16 bf16x8 __attribute__((ext_vector_type(8)));
typedef float  f32x4  __attribute__((ext_vector_type(4)));
typedef __hip_bfloat16 bf;

__device__ __forceinline__ void load_lds16(const void* gp, void* lp) {
    __builtin_amdgcn_global_load_lds(
        (__attribute__((address_space(1))) void*)gp,
        (__attribute__((address_space(3))) void*)lp, 16, 0, 0);
}

__device__ __forceinline__ int4 pack8(float4 a, float4 b) {
    union { bf h[8]; int4 v; } u;
    u.h[0] = __float2bfloat16(a.x); u.h[1] = __float2bfloat16(a.y);
    u.h[2] = __float2bfloat16(a.z); u.h[3] = __float2bfloat16(a.w);
    u.h[4] = __float2bfloat16(b.x); u.h[5] = __float2bfloat16(b.y);
    u.h[6] = __float2bfloat16(b.z); u.h[7] = __float2bfloat16(b.w);
    return u.v;
}

// ---------------------------------------------------------------------------
// bf16 MFMA GEMM: C[M,N] = A[M,K] @ B[N,K]^T (row-major bf16), 128x128 tile.
// A row stride = lda; B row stride = ldb. kchunks>1 -> split-K via blockIdx.z.
// fx==0 -> identity block map (no XCD remap); B2 != null -> M-tiles with
// by>0 use B2 instead of B (merged weight-fold dispatch).
// Af0 != null -> A is fp32, split row-wise over Af0[0,4096) | Af1 | Af2
// (reg-staged + converted to the SAME linear LDS slots as global_load_lds).
// epi: 1 +bias,BN,ReLU -> bf16 | 3 fp32 +bias + addsrc[(gm&(ldc-1))*N+gn] |
//      4 fp32 *exp(*lsp), cols<ldc | 5 bf16 (+bias[n], +biasm[m]) |
//      6 bf16 partial at Cb + z*M*N | 8 fp32 plain partial at Cf + z*M*N
// ---------------------------------------------------------------------------
__global__ __launch_bounds__(256)
void gemm_bf16(const bf* __restrict__ A, const bf* __restrict__ B,
               const bf* __restrict__ B2,
               const float* __restrict__ Af0, const float* __restrict__ Af1,
               const float* __restrict__ Af2,
               int M, int N, int K, int lda, int ldb,
               int kchunks, int fx, int fy, int epi,
               float* __restrict__ Cf, bf* __restrict__ Cb,
               const float* __restrict__ bias, const float* __restrict__ biasm,
               const float* __restrict__ bng, const float* __restrict__ bnb,
               const float* __restrict__ bnm, const float* __restrict__ bnv,
               const float* __restrict__ addsrc, const float* __restrict__ lsp,
               int ldc)
{
    __shared__ __align__(16) short ldsS[8192];   // 16 KB
    short* lsA = ldsS;          // [128][32]
    short* lsB = ldsS + 4096;   // [128][32]

    const int tid  = threadIdx.x;
    const int wave = tid >> 6;
    const int lane = tid & 63;
    const int wm   = wave >> 1;
    const int wn   = wave & 1;
    const int r16  = lane & 15;
    const int quad = lane >> 4;

    // XCD-aware tile remap (fx==0 -> identity)
    int bx, by;
    if (fx == 0) {
        bx = blockIdx.x; by = blockIdx.y;
    } else {
        const int gx = gridDim.x, gy = gridDim.y;
        const int l   = blockIdx.y * gx + blockIdx.x;
        const int xcd = l & 7;
        const int i0  = l >> 3;
        const int sx  = gx / fx, sy = gy / fy;
        bx = (xcd % fx) * sx + (i0 % sx);
        by = (xcd / fx) * sy + (i0 / sx);
    }
    const int bm0 = by * 128;
    const int bn0 = bx * 128;
    const bf* Bp = (B2 && by > 0) ? B2 : B;

    // fp32-A source select (wave-uniform per tile)
    const float* af = nullptr;
    int arow0 = 0;
    if (Af0) {
        if (bm0 < B_ROWS)              { af = Af0; arow0 = bm0; }
        else if (bm0 < B_ROWS + NBANK) { af = Af1; arow0 = bm0 - B_ROWS; }
        else                           { af = Af2; arow0 = bm0 - B_ROWS - NBANK; }
    }

    const int kper = K / kchunks;
    const int kbeg = blockIdx.z * kper;
    const int kend = kbeg + kper;

    f32x4 acc[4][4];
#pragma unroll
    for (int i = 0; i < 4; ++i)
#pragma unroll
        for (int j = 0; j < 4; ++j) acc[i][j] = (f32x4){0.f, 0.f, 0.f, 0.f};

    for (int k0 = kbeg; k0 < kend; k0 += 32) {
#pragma unroll
        for (int i = 0; i < 2; ++i) {
            const int s   = i * 256 + tid;
            const int row = s >> 2;
            const int cc  = (s & 3) * 8;
            const int lofs = (i * 256 + wave * 64) * 16;
            if (af) {
                const float* p = af + (size_t)(arow0 + row) * lda + k0 + cc;
                float4 a = *(const float4*)p;
                float4 b = *(const float4*)(p + 4);
                *(int4*)((char*)lsA + s * 16) = pack8(a, b);
            } else {
                load_lds16(A + (size_t)(bm0 + row) * lda + k0 + cc,
                           (char*)lsA + lofs);
            }
            load_lds16(Bp + (size_t)(bn0 + row) * ldb + k0 + cc, (char*)lsB + lofs);
        }
        __syncthreads();

        bf16x8 afr[4], bfr[4];
#pragma unroll
        for (int i = 0; i < 4; ++i)
            afr[i] = *(const bf16x8*)(lsA + (wm * 64 + i * 16 + r16) * 32 + quad * 8);
#pragma unroll
        for (int j = 0; j < 4; ++j)
            bfr[j] = *(const bf16x8*)(lsB + (wn * 64 + j * 16 + r16) * 32 + quad * 8);
#pragma unroll
        for (int i = 0; i < 4; ++i)
#pragma unroll
            for (int j = 0; j < 4; ++j)
                acc[i][j] = __builtin_amdgcn_mfma_f32_16x16x32_bf16(
                    afr[i], bfr[j], acc[i][j], 0, 0, 0);
        __syncthreads();
    }

    if (epi == 8) {
        float* dst = Cf + (size_t)blockIdx.z * M * N;
#pragma unroll
        for (int i = 0; i < 4; ++i) {
            const int gmb = bm0 + wm * 64 + i * 16 + quad * 4;
#pragma unroll
            for (int j = 0; j < 4; ++j) {
                const int gn = bn0 + wn * 64 + j * 16 + r16;
#pragma unroll
                for (int r = 0; r < 4; ++r)
                    dst[(size_t)(gmb + r) * N + gn] = acc[i][j][r];
            }
        }
        return;
    }

    if (epi == 3 || epi == 4) {
        const float lsv = (epi == 4) ? expf(*lsp) : 1.0f;
#pragma unroll
        for (int i = 0; i < 4; ++i) {
            const int gmb = bm0 + wm * 64 + i * 16 + quad * 4;
#pragma unroll
            for (int j = 0; j < 4; ++j) {
                const int gn = bn0 + wn * 64 + j * 16 + r16;
#pragma unroll
                for (int r = 0; r < 4; ++r) {
                    const int gm = gmb + r;
                    float val = acc[i][j][r];
                    if (epi == 3) {
                        Cf[(size_t)gm * N + gn] =
                            val + bias[gn] + addsrc[(size_t)(gm & (ldc - 1)) * N + gn];
                    } else {
                        if (gn < ldc) Cf[(size_t)gm * ldc + gn] = val * lsv;
                    }
                }
            }
        }
        return;
    }

    // bf16 LDS-staged store path (epi 1, 5, 6)
    bf* dst = Cb + (epi == 6 ? (size_t)blockIdx.z * M * N : 0);
    bf* my  = (bf*)(ldsS + wave * 2048);   // 4 KB per wave: [32][64] bf16

#pragma unroll
    for (int half = 0; half < 2; ++half) {
#pragma unroll
        for (int i2 = 0; i2 < 2; ++i2) {
            const int i = half * 2 + i2;
            const int gmb = bm0 + wm * 64 + i * 16 + quad * 4;
#pragma unroll
            for (int j = 0; j < 4; ++j) {
                const int gn = bn0 + wn * 64 + j * 16 + r16;
#pragma unroll
                for (int r = 0; r < 4; ++r) {
                    float val = acc[i][j][r];
                    if (epi == 1) {
                        val += bias[gn];
                        val = (val - bnm[gn]) * rsqrtf(bnv[gn] + EPS_BN) * bng[gn] + bnb[gn];
                        val = fmaxf(val, 0.f);
                    } else {
                        if (bias)  val += bias[gn];
                        if (biasm) val += biasm[gmb + r];
                    }
                    my[(i2 * 16 + quad * 4 + r) * 64 + j * 16 + r16] =
                        __float2bfloat16(val);
                }
            }
        }
#pragma unroll
        for (int it = 0; it < 4; ++it) {
            const int chunk = it * 64 + lane;
            const int lrow  = chunk >> 3;
            const int lcol  = (chunk & 7) * 8;
            const int grow  = bm0 + wm * 64 + half * 32 + lrow;
            const int gcol  = bn0 + wn * 64 + lcol;
            int4 v = *(const int4*)(my + lrow * 64 + lcol);
            *(int4*)(dst + (size_t)grow * N + gcol) = v;
        }
    }
}

// ---------------------------------------------------------------------------
// h2fuse: per 128-row tile of the 20480-row batch:
//   h1 = relu(A1*(Hp0+Hp1)+C1); h2 = relu(A2*(h1@W2^T)+C2)
//   q tiles  (r0<4096): qt = h2@Wqk^T -> qtb
//   bank tiles: h2 -> h2b, beta[n] = h2.vvec, transposed cols -> h2T
// ---------------------------------------------------------------------------
__global__ __launch_bounds__(256)
void h2fuse(const float* __restrict__ Hp,     // [2][MTOT][128] fp32 partials
            const bf* __restrict__ W2b,       // [128][128]
            const bf* __restrict__ Wqk,       // [128][128]
            const float* __restrict__ bnA,    // A1|C1|A2|C2 (4x128)
            const float* __restrict__ vvecP,  // [16][128]
            bf* __restrict__ h2b, bf* __restrict__ qtb,
            float* __restrict__ beta, bf* __restrict__ h2T)
{
    __shared__ __align__(16) short lsH[16384];   // [128][128] swizzled
    __shared__ __align__(16) short lsW[16384];   // [128][128] swizzled
    __shared__ float sA1[128], sC1[128], sA2[128], sC2[128];

    const int tid  = threadIdx.x;
    const int wave = tid >> 6;
    const int lane = tid & 63;
    const int r16  = lane & 15;
    const int quad = lane >> 4;
    const int wm   = wave >> 1;
    const int wn   = wave & 1;
    const int r0   = blockIdx.x * 128;
    const bool isq = (r0 < B_ROWS);

    // stage W2 (pre-swizzled global source -> linear LDS dest)
#pragma unroll
    for (int m = 0; m < 8; ++m) {
        const int s = m * 256 + tid;
        const int row = s >> 4, pcg = s & 15;
        load_lds16(W2b + row * 128 + (pcg ^ (row & 15)) * 8,
                   (char*)lsW + (m * 256 + wave * 64) * 16);
    }
    if (tid < 128) {
        sA1[tid] = bnA[tid];       sC1[tid] = bnA[128 + tid];
        sA2[tid] = bnA[256 + tid]; sC2[tid] = bnA[384 + tid];
    }
    __syncthreads();

    // h1 tile -> lsH (swizzled bf16)
#pragma unroll
    for (int m = 0; m < 16; ++m) {
        const int s = m * 256 + tid;
        const int row = s >> 5;
        const int col = (s & 31) * 4;
        const float* p0 = Hp + (size_t)(r0 + row) * 128 + col;
        float4 x0 = *(const float4*)p0;
        float4 x1 = *(const float4*)(p0 + (size_t)MTOT * 128);
        union { bf h[4]; int2 v; } u;
        u.h[0] = __float2bfloat16(fmaxf(fmaf(x0.x + x1.x, sA1[col],     sC1[col]),     0.f));
        u.h[1] = __float2bfloat16(fmaxf(fmaf(x0.y + x1.y, sA1[col + 1], sC1[col + 1]), 0.f));
        u.h[2] = __float2bfloat16(fmaxf(fmaf(x0.z + x1.z, sA1[col + 2], sC1[col + 2]), 0.f));
        u.h[3] = __float2bfloat16(fmaxf(fmaf(x0.w + x1.w, sA1[col + 3], sC1[col + 3]), 0.f));
        const int cg = col >> 3;
        *(int2*)((bf*)lsH + row * 128 + ((cg ^ (row & 15)) << 3) + (col & 7)) = u.v;
    }
    __syncthreads();   // lsH + lsW ready

    // pass 1: acc = h1 @ W2^T
    f32x4 acc[4][4];
#pragma unroll
    for (int i = 0; i < 4; ++i)
#pragma unroll
        for (int j = 0; j < 4; ++j) acc[i][j] = (f32x4){0.f, 0.f, 0.f, 0.f};
#pragma unroll
    for (int ks = 0; ks < 4; ++ks) {
        bf16x8 af[4], bfr[4];
#pragma unroll
        for (int i = 0; i < 4; ++i) {
            const int row = wm * 64 + i * 16 + r16;
            af[i] = *(const bf16x8*)(lsH + row * 128 + ((ks * 4 + quad) ^ (row & 15)) * 8);
        }
#pragma unroll
        for (int j = 0; j < 4; ++j) {
            const int row = wn * 64 + j * 16 + r16;
            bfr[j] = *(const bf16x8*)(lsW + row * 128 + ((ks * 4 + quad) ^ (row & 15)) * 8);
        }
#pragma unroll
        for (int i = 0; i < 4; ++i)
#pragma unroll
            for (int j = 0; j < 4; ++j)
                acc[i][j] = __builtin_amdgcn_mfma_f32_16x16x32_bf16(
                    af[i], bfr[j], acc[i][j], 0, 0, 0);
    }
    __syncthreads();   // pass-1 LDS reads complete

    if (isq) {
        // stage Wqk into lsW (dead after pass 1)
#pragma unroll
        for (int m = 0; m < 8; ++m) {
            const int s = m * 256 + tid;
            const int row = s >> 4, pcg = s & 15;
            load_lds16(Wqk + row * 128 + (pcg ^ (row & 15)) * 8,
                       (char*)lsW + (m * 256 + wave * 64) * 16);
        }
    }

    // epilogue: h2 = relu(A2*acc+C2) -> lsH (swizzled, overwrites h1)
#pragma unroll
    for (int i = 0; i < 4; ++i) {
#pragma unroll
        for (int j = 0; j < 4; ++j) {
            const int gn = wn * 64 + j * 16 + r16;
            const int cg = gn >> 3, cl = gn & 7;
            const float a2 = sA2[gn], c2 = sC2[gn];
#pragma unroll
            for (int r = 0; r < 4; ++r) {
                const int row = wm * 64 + i * 16 + quad * 4 + r;
                float v = fmaxf(fmaf(acc[i][j][r], a2, c2), 0.f);
                ((bf*)lsH)[row * 128 + ((cg ^ (row & 15)) << 3) + cl] =
                    __float2bfloat16(v);
            }
        }
    }
    __syncthreads();   // lsH(h2) visible; Wqk staging drained

    if (!isq) {
        // ---- bank tile: h2 -> h2b, beta, h2T columns ----
#pragma unroll
        for (int m = 0; m < 8; ++m) {
            const int s = m * 256 + tid;
            const int row = s >> 4, cg = s & 15;
            *(int4*)(h2b + (size_t)(r0 + row) * 128 + cg * 8) =
                *(const int4*)(lsH + row * 128 + ((cg ^ (row & 15)) << 3));
        }
        // vvec into sA1 (dead); barrier before cross-thread read
        if (tid < 128) {
            float s = 0.f;
#pragma unroll
            for (int z = 0; z < 16; ++z) s += vvecP[z * 128 + tid];
            sA1[tid] = s;
        }
        __syncthreads();
        const int nb0 = r0 - B_ROWS;
        // beta: 2 threads per row
        {
            const int row = tid >> 1, hf = tid & 1;
            float s = 0.f;
#pragma unroll
            for (int g = 0; g < 8; ++g) {
                const int cg = hf * 8 + g;
                bf16x8 v = *(const bf16x8*)(lsH + row * 128 + ((cg ^ (row & 15)) << 3));
#pragma unroll
                for (int e = 0; e < 8; ++e)
                    s += __bfloat162float((bf)v[e]) * sA1[cg * 8 + e];
            }
            s += __shfl_xor(s, 1, 64);
            if (hf == 0) beta[nb0 + row] = s;
        }
        // h2T: h2T[p][nb0+n] = h2[n][p]
#pragma unroll
        for (int m = 0; m < 8; ++m) {
            const int idx = m * 256 + tid;   // 0..2047
            const int p  = idx >> 4;
            const int ng = (idx & 15) * 8;
            union { bf h[8]; int4 v; } u;
#pragma unroll
            for (int e = 0; e < 8; ++e) {
                const int n = ng + e;
                u.h[e] = ((bf*)lsH)[n * 128 + (((p >> 3) ^ (n & 15)) << 3) + (p & 7)];
            }
            *(int4*)(h2T + (size_t)p * (2 * NBANK) + nb0 + ng) = u.v;
        }
        return;
    }

    // ---- q tile: pass 2: qt = h2 @ Wqk^T ----
    f32x4 acc2[4][4];
#pragma unroll
    for (int i = 0; i < 4; ++i)
#pragma unroll
        for (int j = 0; j < 4; ++j) acc2[i][j] = (f32x4){0.f, 0.f, 0.f, 0.f};
#pragma unroll
    for (int ks = 0; ks < 4; ++ks) {
        bf16x8 af[4], bfr[4];
#pragma unroll
        for (int i = 0; i < 4; ++i) {
            const int row = wm * 64 + i * 16 + r16;
            af[i] = *(const bf16x8*)(lsH + row * 128 + ((ks * 4 + quad) ^ (row & 15)) * 8);
        }
#pragma unroll
        for (int j = 0; j < 4; ++j) {
            const int row = wn * 64 + j * 16 + r16;
            bfr[j] = *(const bf16x8*)(lsW + row * 128 + ((ks * 4 + quad) ^ (row & 15)) * 8);
        }
#pragma unroll
        for (int i = 0; i < 4; ++i)
#pragma unroll
            for (int j = 0; j < 4; ++j)
                acc2[i][j] = __builtin_amdgcn_mfma_f32_16x16x32_bf16(
                    af[i], bfr[j], acc2[i][j], 0, 0, 0);
    }
    __syncthreads();   // lsW (Wqk) reads complete before my-region overwrite

    bf* my  = (bf*)lsW + wave * 2048;   // [32][64] per wave
    bf* dst = qtb + (size_t)r0 * 128;
#pragma unroll
    for (int half = 0; half < 2; ++half) {
#pragma unroll
        for (int i2 = 0; i2 < 2; ++i2) {
            const int i = half * 2 + i2;
#pragma unroll
            for (int j = 0; j < 4; ++j)
#pragma unroll
                for (int r = 0; r < 4; ++r)
                    my[(i2 * 16 + quad * 4 + r) * 64 + j * 16 + r16] =
                        __float2bfloat16(acc2[i][j][r]);
        }
#pragma unroll
        for (int it = 0; it < 4; ++it) {
            const int chunk = it * 64 + lane;
            const int lrow  = chunk >> 3;
            const int lcol  = (chunk & 7) * 8;
            const int grow  = wm * 64 + half * 32 + lrow;
            const int gcol  = wn * 64 + lcol;
            int4 v = *(const int4*)(my + lrow * 64 + lcol);
            *(int4*)(dst + (size_t)grow * 128 + gcol) = v;
        }
    }
}

// ---------------------------------------------------------------------------
// Fused attention (R9 + double-buffered K/V staging, T3-minimum 2-phase):
// 8 waves x 16 q-rows, 80 KB LDS (K,V x2 + S). VGPR (~128/lane) already caps
// at 2 blocks/CU, so dbuf LDS is free. One barrier per chunk; stage(c+1)
// issued before compute(c) so HBM/L2 latency hides under MFMA.
// ---------------------------------------------------------------------------
__global__ __launch_bounds__(512)
void attn_fused(const bf* __restrict__ qt,      // [4096][128]
                const bf* __restrict__ h2bank,  // [16384][128] side-major
                const bf* __restrict__ h2T,     // [128][16384]
                const float* __restrict__ beta, // [16384]
                bf* __restrict__ Ypart,         // [32][4096][128]
                float* __restrict__ rsP)        // [32][4096]
{
    __shared__ __align__(16) short lds[40960];   // 80 KB -> 2 blocks/CU
    // lsK[b] = lds + b*8192   : [64][128], phys cg = cg ^ (row&15)
    // lsV[b] = lds + 16384 + b*8192 : [128][64], phys cg = cg ^ (row&7)
    short* lsS = lds + 32768;    // [128][64], phys cg = cg ^ (row&7)

    const int tid  = threadIdx.x;
    const int wave = tid >> 6;
    const int lane = tid & 63;
    const int r16  = lane & 15;
    const int quad = lane >> 4;

    const int qb   = blockIdx.x >> 5;
    const int side = (blockIdx.x >> 4) & 1;
    const int seg  = blockIdx.x & 15;
    const int part = side * KVSEG + seg;
    const int nseg0 = seg * (NBANK / KVSEG);
    const bf* kbase = h2bank + (size_t)side * NBANK * P_DIM;
    const int ncol0 = side * NBANK;

    const bf* qrow = qt + (size_t)(qb * 128 + wave * 16 + r16) * P_DIM;
    bf16x8 qreg[4];
#pragma unroll
    for (int ks = 0; ks < 4; ++ks)
        qreg[ks] = *(const bf16x8*)(qrow + (ks * 4 + quad) * 8);

    f32x4 yacc[8];
    float rsacc[4] = {0.f, 0.f, 0.f, 0.f};
#pragma unroll
    for (int j = 0; j < 8; ++j) yacc[j] = (f32x4){0.f, 0.f, 0.f, 0.f};

    auto stage = [&](int buf, int kv0) {
        short* dK = lds + buf * 8192;
        short* dV = lds + 16384 + buf * 8192;
#pragma unroll
        for (int m = 0; m < 2; ++m) {
            const int s = m * 512 + tid;
            const int row = s >> 4, pcg = s & 15;
            const int lcg = pcg ^ (row & 15);
            load_lds16(kbase + (size_t)(kv0 + row) * P_DIM + lcg * 8,
                       (char*)dK + (m * 512 + wave * 64) * 16);
        }
#pragma unroll
        for (int m = 0; m < 2; ++m) {
            const int s = m * 512 + tid;
            const int row = s >> 3, pcg = s & 7;
            const int lcg = pcg ^ (row & 7);
            load_lds16(h2T + (size_t)row * (2 * NBANK) + ncol0 + kv0 + lcg * 8,
                       (char*)dV + (m * 512 + wave * 64) * 16);
        }
    };

    stage(0, nseg0);            // prologue
    int cur = 0;

    for (int c = 0; c < CHUNKS; ++c) {
        __syncthreads();        // buf[cur] staged (vmcnt drained); buf[cur^1]
                                // readers (chunk c-1) all past this point
        if (c + 1 < CHUNKS) stage(cur ^ 1, nseg0 + (c + 1) * KCH);

        short* lsK = lds + cur * 8192;
        short* lsV = lds + 16384 + cur * 8192;
        const int kv0 = nseg0 + c * KCH;

        f32x4 sacc[4];
#pragma unroll
        for (int j = 0; j < 4; ++j) sacc[j] = (f32x4){0.f, 0.f, 0.f, 0.f};
        __builtin_amdgcn_s_setprio(1);
#pragma unroll
        for (int ks = 0; ks < 4; ++ks) {
            bf16x8 bfr[4];
#pragma unroll
            for (int j = 0; j < 4; ++j) {
                const int kr = j * 16 + r16;
                bfr[j] = *(const bf16x8*)(lsK + kr * 128 +
                                          ((ks * 4 + quad) ^ (kr & 15)) * 8);
            }
#pragma unroll
            for (int j = 0; j < 4; ++j)
                sacc[j] = __builtin_amdgcn_mfma_f32_16x16x32_bf16(
                    qreg[ks], bfr[j], sacc[j], 0, 0, 0);
        }
        __builtin_amdgcn_s_setprio(0);

#pragma unroll
        for (int j = 0; j < 4; ++j) {
            const int col = j * 16 + r16;
            const float bv = beta[(size_t)side * NBANK + kv0 + col];
            const int cg = col >> 3, cl = col & 7;
#pragma unroll
            for (int r = 0; r < 4; ++r) {
                const int row = wave * 16 + quad * 4 + r;
                float v = __expf(SCALE_S * (sacc[j][r] + bv));
                rsacc[r] += v;
                ((bf*)lsS)[row * 64 + ((cg ^ (row & 7)) << 3) + cl] =
                    __float2bfloat16(v);
            }
        }

        __builtin_amdgcn_s_setprio(1);
#pragma unroll
        for (int ks = 0; ks < 2; ++ks) {
            const int sr = wave * 16 + r16;
            bf16x8 pa = *(const bf16x8*)(lsS + sr * 64 +
                                         ((ks * 4 + quad) ^ (sr & 7)) * 8);
            bf16x8 pb[8];
#pragma unroll
            for (int j = 0; j < 8; ++j) {
                const int vr = j * 16 + r16;
                pb[j] = *(const bf16x8*)(lsV + vr * 64 +
                                         ((ks * 4 + quad) ^ (vr & 7)) * 8);
            }
#pragma unroll
            for (int j = 0; j < 8; ++j)
                yacc[j] = __builtin_amdgcn_mfma_f32_16x16x32_bf16(
                    pa, pb[j], yacc[j], 0, 0, 0);
        }
        __builtin_amdgcn_s_setprio(0);
        cur ^= 1;
    }

#pragma unroll
    for (int r = 0; r < 4; ++r) {
        float s = rsacc[r];
        s += __shfl_xor(s, 1, 64);
        s += __shfl_xor(s, 2, 64);
        s += __shfl_xor(s, 4, 64);
        s += __shfl_xor(s, 8, 64);
        rsacc[r] = s;
    }
    if (r16 == 0)
        *(float4*)(rsP + (size_t)part * B_ROWS + qb * 128 + wave * 16 + quad * 4) =
            (float4){rsacc[0], rsacc[1], rsacc[2], rsacc[3]};

    __syncthreads();
    bf* my = (bf*)lds + wave * 2048;   // [16][128] bf16 = 4 KB per wave
#pragma unroll
    for (int j = 0; j < 8; ++j)
#pragma unroll
        for (int r = 0; r < 4; ++r)
            my[(quad * 4 + r) * 128 + j * 16 + r16] =
                __float2bfloat16(yacc[j][r]);
    bf* dst = Ypart + (size_t)part * B_ROWS * P_DIM
                    + (size_t)(qb * 128 + wave * 16) * P_DIM;
#pragma unroll
    for (int it = 0; it < 4; ++it) {
        const int chunk = it * 64 + lane;       // 0..255 int4s
        const int lrow  = chunk >> 4;
        const int lcol  = (chunk & 15) * 8;
        *(int4*)(dst + (size_t)lrow * P_DIM + lcol) =
            *(const int4*)(my + lrow * 128 + lcol);
    }
}

// ---------------------------------------------------------------------------
// prep mega-kernel (convX removed -- GEMM1 now reads fp32 inputs directly):
//  r0 convW | r1 convW3T | r2 ftpad | r3 vvecP | r4 bvp | r5 BN coeffs
// ---------------------------------------------------------------------------
#define PG0 584     // convW
#define PG1 64      // convW3T
#define PG2 512     // ftpad
#define PG3 8       // vvecP partials
#define PG4 256     // bvp
#define PG5 1       // folded BN coefficients A1|C1|A2|C2

__global__ __launch_bounds__(256)
void prep(const float* __restrict__ W1, const float* __restrict__ W2,
          const float* __restrict__ Wp,
          const float* __restrict__ W3, const float* __restrict__ b3,
          const float* __restrict__ bp, const float* __restrict__ Ft,
          const float* __restrict__ b1, const float* __restrict__ g1,
          const float* __restrict__ be1, const float* __restrict__ m1,
          const float* __restrict__ v1,
          const float* __restrict__ b2, const float* __restrict__ g2,
          const float* __restrict__ be2, const float* __restrict__ m2,
          const float* __restrict__ v2,
          bf* __restrict__ W1b, bf* __restrict__ W2b, bf* __restrict__ Wpb,
          bf* __restrict__ Tq, bf* __restrict__ Tk, bf* __restrict__ Tv,
          bf* __restrict__ Ftb,
          float* __restrict__ vvecP, float* __restrict__ bvp,
          float* __restrict__ bnA)
{
    const int tid = threadIdx.x;
    int b = blockIdx.x;
    if (b < PG0) {                       // ---- convW: W1|W2|Wp -> bf16
        int i = (b * 256 + tid) * 8;
        const int n1 = P_DIM * D_DIM, n2 = n1 + P_DIM * P_DIM;
        const float* src; bf* dst; int off;
        if (i < n1)      { src = W1; dst = W1b; off = i; }
        else if (i < n2) { src = W2; dst = W2b; off = i - n1; }
        else             { src = Wp; dst = Wpb; off = i - n2; }
        float4 a = *(const float4*)(src + off);
        float4 c = *(const float4*)(src + off + 4);
        *(int4*)(dst + off) = pack8(a, c);
        return;
    }
    if ((b -= PG0) < PG1) {              // ---- convW3T: Txx[p,d] = W3[3d+x,p]
        int i = (b * 256 + tid) * 8;
        int p = i >> 10, d0 = i & 1023;
        union { bf h[8]; int4 v; } uq, uk, uv;
#pragma unroll
        for (int j = 0; j < 8; ++j) {
            const float* r = W3 + (size_t)3 * (d0 + j) * P_DIM + p;
            uq.h[j] = __float2bfloat16(r[0]);
            uk.h[j] = __float2bfloat16(r[P_DIM]);
            uv.h[j] = __float2bfloat16(r[2 * P_DIM]);
        }
        *(int4*)(Tq + i) = uq.v;
        *(int4*)(Tk + i) = uk.v;
        *(int4*)(Tv + i) = uv.v;
        return;
    }
    if ((b -= PG1) < PG2) {              // ---- ftpad
        int i = (b * 256 + tid) * 8;
        int row = i >> 10, col = i & 1023;
        if (row < C_CLS) {
            float4 a = *(const float4*)(Ft + (size_t)row * D_DIM + col);
            float4 c = *(const float4*)(Ft + (size_t)row * D_DIM + col + 4);
            *(int4*)(Ftb + i) = pack8(a, c);
        } else {
            *(int4*)(Ftb + i) = (int4){0, 0, 0, 0};
        }
        return;
    }
    if ((b -= PG2) < PG3) {              // ---- vvecP partials of W3k^T b3q
        const int p = tid & 127, hf = tid >> 7;
        const int dbase = b * 128 + hf * 64;
        float s = 0.f;
        for (int dd = 0; dd < 64; ++dd) {
            const int d = dbase + dd;
            s = fmaf(b3[3 * d], W3[(size_t)(3 * d + 1) * P_DIM + p], s);
        }
        vvecP[(b * 2 + hf) * P_DIM + p] = s;
        return;
    }
    if ((b -= PG3) < PG4) {              // ---- bvp[o] = Wp[o,:].b3v + bp[o]
        const int wave = tid >> 6, lane = tid & 63;
        const int o = b * 4 + wave;
        const float* r = Wp + (size_t)o * D_DIM;
        float s = 0.f;
        for (int i = lane; i < D_DIM; i += 64) s = fmaf(r[i], b3[3 * i + 2], s);
        for (int off = 32; off > 0; off >>= 1) s += __shfl_down(s, off, 64);
        if (lane == 0) bvp[o] = s + bp[o];
        return;
    }
    // ---- folded BN coefficients
    if (tid < 128) {
        float a1 = g1[tid] * rsqrtf(v1[tid] + EPS_BN);
        bnA[tid]       = a1;
        bnA[128 + tid] = (b1[tid] - m1[tid]) * a1 + be1[tid];
        float a2 = g2[tid] * rsqrtf(v2[tid] + EPS_BN);
        bnA[256 + tid] = a2;
        bnA[384 + tid] = (b2[tid] - m2[tid]) * a2 + be2[tid];
    }
}

// fused reduce for the merged weight-fold GEMM: WWp = [8][1152][128] bf16;
// rows 0-127 of each part -> Wqk, rows 128-1151 -> Wpv.
__global__ __launch_bounds__(256)
void reduceWW(const bf* __restrict__ WWp,
              bf* __restrict__ Wqk, bf* __restrict__ Wpv)
{
    const int tid = threadIdx.x;
    const size_t pstride = (size_t)1152 * 128;
    if (blockIdx.x < 8) {
        int i = (blockIdx.x * 256 + tid) * 8;          // < 16384
        float s[8] = {};
        for (int z = 0; z < 8; ++z) {
            union { int4 v; bf h[8]; } u;
            u.v = *(const int4*)(WWp + (size_t)z * pstride + i);
#pragma unroll
            for (int e = 0; e < 8; ++e) s[e] += __bfloat162float(u.h[e]);
        }
        union { bf h[8]; int4 v; } o;
#pragma unroll
        for (int e = 0; e < 8; ++e) o.h[e] = __float2bfloat16(s[e]);
        *(int4*)(Wqk + i) = o.v;
    } else {
        int i = ((blockIdx.x - 8) * 256 + tid) * 8;    // < 131072
        float s[8] = {};
        for (int z = 0; z < 8; ++z) {
            union { int4 v; bf h[8]; } u;
            u.v = *(const int4*)(WWp + (size_t)z * pstride + 16384 + i);
#pragma unroll
            for (int e = 0; e < 8; ++e) s[e] += __bfloat162float(u.h[e]);
        }
        union { bf h[8]; int4 v; } o;
#pragma unroll
        for (int e = 0; e < 8; ++e) o.h[e] = __float2bfloat16(s[e]);
        *(int4*)(Wpv + i) = o.v;
    }
}

// reduceY: Yhat[s][b][p] = sum_z parts[s*16+z][b][p] / (sum_g rsP[s*16+g][b])
__global__ __launch_bounds__(256)
void reduceY(const bf* __restrict__ parts, const float* __restrict__ rsP,
             bf* __restrict__ Yhat)
{
    int j = (blockIdx.x * 256 + threadIdx.x) * 8;      // < 2*B_ROWS*P_DIM
    const int s = j >> 19;                             // B_ROWS*P_DIM = 2^19
    const int qrow = (j >> 7) & (B_ROWS - 1);
    float rs = 0.f;
#pragma unroll
    for (int g = 0; g < KVSEG; ++g)
        rs += rsP[(size_t)(s * KVSEG + g) * B_ROWS + qrow];
    const bf* p = parts + (size_t)s * KVSEG * 524288 + (size_t)(j & 524287);
    float acc[8] = {};
    for (int z = 0; z < KVSEG; ++z) {
        union { int4 v; bf h[8]; } u;
        u.v = *(const int4*)(p + (size_t)z * 524288);
#pragma unroll
        for (int e = 0; e < 8; ++e) acc[e] += __bfloat162float(u.h[e]);
    }
    const float inv = 1.0f / rs;
    union { bf h[8]; int4 v; } o;
#pragma unroll
    for (int e = 0; e < 8; ++e) o.h[e] = __float2bfloat16(acc[e] * inv);
    *(int4*)(Yhat + j) = o.v;
}

// dual row L2-normalize + bf16 out
__global__ __launch_bounds__(256)
void rownorm2b(const float* __restrict__ G, bf* __restrict__ out)
{
    __shared__ float red[16];
    const int tid = threadIdx.x;
    const float* ps = G + (size_t)blockIdx.x * D_DIM;
    const float* pt = ps + (size_t)B_ROWS * D_DIM;
    float4 a = *(const float4*)(ps + tid * 4);
    float4 c = *(const float4*)(pt + tid * 4);
    float sa = a.x * a.x + a.y * a.y + a.z * a.z + a.w * a.w;
    float sb = c.x * c.x + c.y * c.y + c.z * c.z + c.w * c.w;
    for (int s = 32; s > 0; s >>= 1) {
        sa += __shfl_down(sa, s, 64);
        sb += __shfl_down(sb, s, 64);
    }
    if ((tid & 63) == 0) { red[tid >> 6] = sa; red[8 + (tid >> 6)] = sb; }
    __syncthreads();
    if (tid == 0) {
        float ta = 0.f, tb = 0.f;
        for (int w = 0; w < 4; ++w) { ta += red[w]; tb += red[8 + w]; }
        red[4] = rsqrtf(ta); red[12] = rsqrtf(tb);
    }
    __syncthreads();
    const float ia = red[4], ib = red[12];
    union { bf h[4]; int2 v; } o;
    o.h[0] = __float2bfloat16(a.x * ia + c.x * ib);
    o.h[1] = __float2bfloat16(a.y * ia + c.y * ib);
    o.h[2] = __float2bfloat16(a.z * ia + c.z * ib);
    o.h[3] = __float2bfloat16(a.w * ia + c.w * ib);
    *(int2*)(out + (size_t)blockIdx.x * D_DIM + tid * 4) = o.v;
}

// ---------------------------------------------------------------------------
// R10: (a) convX eliminated -- GEMM1 reads fp32 Fv/Fvs/Fvt directly via
// reg-staged A conversion (saves ~84 MB HBM + one dispatch); (b) attn_fused
// K/V staging double-buffered (80 KB LDS, free at 2 blocks/CU; 1 barrier/chunk).
// ---------------------------------------------------------------------------
extern "C" void kernel_launch(void* const* d_in, const int* in_sizes, int n_in,
                              void* d_out, int out_size, void* d_ws, size_t ws_size,
                              hipStream_t stream)
{
    (void)in_sizes; (void)n_in; (void)out_size; (void)ws_size;

    const float* Ft  = (const float*)d_in[0];
    const float* Fv  = (const float*)d_in[1];
    const float* Fvs = (const float*)d_in[2];
    const float* Fvt = (const float*)d_in[3];
    const float* W1  = (const float*)d_in[4];
    const float* b1  = (const float*)d_in[5];
    const float* g1  = (const float*)d_in[6];
    const float* be1 = (const float*)d_in[7];
    const float* m1  = (const float*)d_in[8];
    const float* v1  = (const float*)d_in[9];
    const float* W2  = (const float*)d_in[10];
    const float* b2  = (const float*)d_in[11];
    const float* g2  = (const float*)d_in[12];
    const float* be2 = (const float*)d_in[13];
    const float* m2  = (const float*)d_in[14];
    const float* v2  = (const float*)d_in[15];
    const float* W3  = (const float*)d_in[16];
    const float* b3  = (const float*)d_in[17];
    const float* Wp  = (const float*)d_in[18];
    const float* bp  = (const float*)d_in[19];
    const float* ls  = (const float*)d_in[20];

    char* base = (char*)d_ws;
    size_t o = 0;
    auto take = [&](size_t s) { size_t r = o; o += (s + 255) & ~(size_t)255; return r; };

    // persistent (~25 MB). NOTE: W3kT and Wpb MUST be contiguous (merged fold
    // GEMM treats them as one 1152-row A matrix; sizes are 256B-multiples).
    bf* qtb   = (bf*)(base + take((size_t)B_ROWS * P_DIM * 2));
    bf* h2T   = (bf*)(base + take((size_t)P_DIM * 2 * NBANK * 2));
    bf* Yhat  = (bf*)(base + take((size_t)2 * B_ROWS * P_DIM * 2));
    bf* Ftb   = (bf*)(base + take((size_t)D_DIM * D_DIM * 2));
    bf* W3qT  = (bf*)(base + take((size_t)P_DIM * D_DIM * 2));
    bf* W3kT  = (bf*)(base + take((size_t)P_DIM * D_DIM * 2));
    bf* Wpb   = (bf*)(base + take((size_t)D_DIM * D_DIM * 2));   // after W3kT!
    bf* W3vT  = (bf*)(base + take((size_t)P_DIM * D_DIM * 2));
    bf* Wqk   = (bf*)(base + take((size_t)P_DIM * P_DIM * 2));
    bf* Wpvb  = (bf*)(base + take((size_t)D_DIM * P_DIM * 2));
    bf* W1b   = (bf*)(base + take((size_t)P_DIM * D_DIM * 2));
    bf* W2b   = (bf*)(base + take((size_t)P_DIM * P_DIM * 2));
    bf* h2b   = (bf*)(base + take((size_t)MTOT * P_DIM * 2));
    bf* WWp   = (bf*)(base + take((size_t)8 * 1152 * P_DIM * 2));
    float* vvecP = (float*)(base + take((size_t)16 * P_DIM * 4));
    float* beta  = (float*)(base + take((size_t)2 * NBANK * 4));
    float* bvp   = (float*)(base + take(D_DIM * 4));
    float* bnA   = (float*)(base + take(4 * P_DIM * 4));
    float* rsP   = (float*)(base + take((size_t)2 * KVSEG * B_ROWS * 4));

    // scratch region (aliased across phases)
    const size_t Dbase = o;
    float* Hp    = (float*)(base + Dbase);                               // 21 MB
    bf*    Opart = (bf*)(base + Dbase + (size_t)64 * 1024 * 1024);       // 32 MB
    float* G     = (float*)(base + Dbase);                               // 32 MB
    bf*    Fsumb = (bf*)(base + Dbase + (size_t)2 * B_ROWS * D_DIM * 4); // 8 MB

    auto gemm = [&](const bf* A, const bf* B, const bf* B2,
                    const float* Af0, const float* Af1, const float* Af2,
                    int M, int N, int K, int lda, int ldb,
                    int kch, int fx, int fy, int epi, float* Cf, bf* Cb,
                    const float* bias, const float* biasm,
                    const float* bg, const float* bb, const float* bm, const float* bv,
                    const float* addsrc, const float* lsp, int ldc) {
        gemm_bf16<<<dim3(N / 128, M / 128, kch), dim3(256), 0, stream>>>(
            A, B, B2, Af0, Af1, Af2, M, N, K, lda, ldb, kch, fx, fy, epi,
            Cf, Cb, bias, biasm, bg, bb, bm, bv, addsrc, lsp, ldc);
    };

    // 1) prep: weight transforms + folded BN coefficients (convX removed)
    prep<<<dim3(PG0 + PG1 + PG2 + PG3 + PG4 + PG5), dim3(256), 0, stream>>>(
        W1, W2, Wp, W3, b3, bp, Ft,
        b1, g1, be1, m1, v1, b2, g2, be2, m2, v2,
        W1b, W2b, Wpb, W3qT, W3kT, W3vT, Ftb, vvecP, bvp, bnA);

    // 2) merged weight folds: A = [W3kT; Wpb] (1152 rows), B tile 0 = W3qT
    //    (-> Wqk rows), tiles 1-8 = W3vT (-> Wpv rows); split-K 8.
    gemm(W3kT, W3qT, W3vT, nullptr, nullptr, nullptr,
         1152, P_DIM, D_DIM, D_DIM, D_DIM, 8, 0, 0, 6,
         nullptr, WWp, nullptr, nullptr, nullptr, nullptr, nullptr, nullptr,
         nullptr, nullptr, 0);
    // 3) fused reduces
    reduceWW<<<dim3(72), dim3(256), 0, stream>>>(WWp, Wqk, Wpvb);

    // 4) pre_project GEMM1, fp32-A direct (Fv|Fvs|Fvt), split-K fp32 partials
    gemm(nullptr, W1b, nullptr, Fv, Fvs, Fvt,
         MTOT, P_DIM, D_DIM, D_DIM, D_DIM, 2, 1, 8, 8,
         Hp, nullptr, nullptr, nullptr, nullptr, nullptr, nullptr, nullptr,
         nullptr, nullptr, 0);
    // 5) h2fuse: partial-sum + BN1/ReLU + GEMM2 + BN2/ReLU + {Qtilde | beta,h2T}
    h2fuse<<<dim3(MTOT / 128), dim3(256), 0, stream>>>(
        Hp, W2b, Wqk, bnA, vvecP, h2b, qtb, beta, h2T);

    // 6) fused attention: S in LDS only; Y/rowsum seg partials
    attn_fused<<<dim3(2 * KVSEG * (B_ROWS / 128)), dim3(512), 0, stream>>>(
        qtb, h2b + (size_t)B_ROWS * P_DIM, h2T, beta, Opart, rsP);
    // 7) fold segments + softmax normalize -> Yhat [2*B_ROWS,128]
    reduceY<<<dim3(2 * B_ROWS * P_DIM / 2048), dim3(256), 0, stream>>>(
        Opart, rsP, Yhat);

    // 8) combined post-project (K=128) + residual
    gemm(Yhat, Wpvb, nullptr, nullptr, nullptr, nullptr,
         2 * B_ROWS, D_DIM, P_DIM, P_DIM, P_DIM, 1, 1, 8, 3,
         G, nullptr, bvp, nullptr, nullptr, nullptr, nullptr, nullptr, Fv,
         nullptr, B_ROWS);
    // 9) dual rownorm -> bf16
    rownorm2b<<<dim3(B_ROWS), dim3(256), 0, stream>>>(G, Fsumb);
    // 10) logits
    gemm(Fsumb, Ftb, nullptr, nullptr, nullptr, nullptr,
         B_ROWS, D_DIM, D_DIM, D_DIM, D_DIM, 1, 1, 8, 4,
         (float*)d_out, nullptr, nullptr, nullptr, nullptr, nullptr, nullptr,
         nullptr, nullptr, ls, C_CLS);
}